// Round 10
// baseline (1151.670 us; speedup 1.0000x reference)
//
#include <hip/hip_runtime.h>
#include <math.h>
#include <stdint.h>

// GPT fwd, L=4 D=1024 H=16 HS=64 F=4096 V=50257 S=2048.
// Round 10: gemm256p v2 — XCD-aware persistent tile map (B panel shared
// within one XCD's L2), reordered stage ledger (B01,B23,A0A2,A1A3 with
// vmcnt(2)@pre-q0 / vmcnt(4)@pre-q2 so HBM-class loads get 3-4 phases of
// slack and L2-class A gets 2). Layers unchanged from R9.

#define SEQ 2048
#define DIM 1024
#define NHEAD 16
#define FFN 4096
#define VOCAB 50257
#define NLAYER 4
#define LNEPS 1e-5f
#define QKVD 3072
#define KVB 128

using bf16x8 = __attribute__((ext_vector_type(8))) short;
using s16x4  = __attribute__((ext_vector_type(4))) short;
using f32x4  = __attribute__((ext_vector_type(4))) float;
using fl4    = __attribute__((ext_vector_type(4))) float;

static __device__ __forceinline__ short f2bf(float f) {
  uint32_t u = __float_as_uint(f);
  u = (u + 0x7fffu + ((u >> 16) & 1u)) >> 16;
  return (short)u;
}
static __device__ __forceinline__ float bf2f(short s) {
  return __uint_as_float(((uint32_t)(uint16_t)s) << 16);
}
static __device__ __forceinline__ void gload_lds16(const void* g, void* l) {
  __builtin_amdgcn_global_load_lds((const __attribute__((address_space(1))) void*)g,
                                   (__attribute__((address_space(3))) void*)l, 16, 0, 0);
}

// ---------------- embedding (fp32 h) ----------------
__global__ void embed_kernel(const int* __restrict__ ids,
                             const float* __restrict__ tok,
                             const float* __restrict__ pos,
                             float* __restrict__ h) {
  int i = blockIdx.x * blockDim.x + threadIdx.x;
  if (i < SEQ * DIM) {
    int s = i / DIM, d = i % DIM;
    h[i] = tok[(long)ids[s] * DIM + d] + pos[i];
  }
}

// ---------------- layernorm: fp32 in -> bf16 out (layer0 ln1 only) ----------------
__global__ void ln_kernel(const float* __restrict__ x, const float* __restrict__ w,
                          const float* __restrict__ b, short* __restrict__ y) {
  int row = blockIdx.x;
  const float* xr = x + (long)row * DIM;
  short* yr = y + (long)row * DIM;
  int tid = threadIdx.x;
  float v0 = xr[tid], v1 = xr[tid + 256], v2 = xr[tid + 512], v3 = xr[tid + 768];
  __shared__ float red[8];
  float s = v0 + v1 + v2 + v3;
#pragma unroll
  for (int o = 32; o >= 1; o >>= 1) s += __shfl_xor(s, o);
  if ((tid & 63) == 0) red[tid >> 6] = s;
  __syncthreads();
  float mean = (red[0] + red[1] + red[2] + red[3]) * (1.f / DIM);
  float d0 = v0 - mean, d1 = v1 - mean, d2 = v2 - mean, d3 = v3 - mean;
  float q = d0 * d0 + d1 * d1 + d2 * d2 + d3 * d3;
#pragma unroll
  for (int o = 32; o >= 1; o >>= 1) q += __shfl_xor(q, o);
  if ((tid & 63) == 0) red[4 + (tid >> 6)] = q;
  __syncthreads();
  float var = (red[4] + red[5] + red[6] + red[7]) * (1.f / DIM);
  float rstd = rsqrtf(var + LNEPS);
  yr[tid]       = f2bf(d0 * rstd * w[tid] + b[tid]);
  yr[tid + 256] = f2bf(d1 * rstd * w[tid + 256] + b[tid + 256]);
  yr[tid + 512] = f2bf(d2 * rstd * w[tid + 512] + b[tid + 512]);
  yr[tid + 768] = f2bf(d3 * rstd * w[tid + 768] + b[tid + 768]);
}

// ---------------- fused: h += bias + part0 + part1; x = LN(h) bf16 ----------------
__global__ void reduce_ln(const float* __restrict__ part, const float* __restrict__ bias,
                          const float* __restrict__ lnw, const float* __restrict__ lnb,
                          float* __restrict__ h, short* __restrict__ x) {
  const long MN = (long)SEQ * DIM;
  int row = blockIdx.x, tid = threadIdx.x;
  long off = (long)row * DIM + tid * 4;
  fl4 hv = *(const fl4*)(h + off);
  fl4 p0 = *(const fl4*)(part + off);
  fl4 p1 = *(const fl4*)(part + MN + off);
  fl4 bv = *(const fl4*)(bias + tid * 4);
  float v[4];
#pragma unroll
  for (int u = 0; u < 4; u++) v[u] = hv[u] + p0[u] + p1[u] + bv[u];
  __shared__ float red[8];
  float s = v[0] + v[1] + v[2] + v[3];
#pragma unroll
  for (int o = 32; o >= 1; o >>= 1) s += __shfl_xor(s, o);
  if ((tid & 63) == 0) red[tid >> 6] = s;
  __syncthreads();
  float mean = (red[0] + red[1] + red[2] + red[3]) * (1.f / DIM);
  float d[4], q = 0.f;
#pragma unroll
  for (int u = 0; u < 4; u++) { d[u] = v[u] - mean; q += d[u] * d[u]; }
#pragma unroll
  for (int o = 32; o >= 1; o >>= 1) q += __shfl_xor(q, o);
  if ((tid & 63) == 0) red[4 + (tid >> 6)] = q;
  fl4 hw; hw[0] = v[0]; hw[1] = v[1]; hw[2] = v[2]; hw[3] = v[3];
  *(fl4*)(h + off) = hw;
  __syncthreads();
  float var = (red[4] + red[5] + red[6] + red[7]) * (1.f / DIM);
  float rstd = rsqrtf(var + LNEPS);
  fl4 w = *(const fl4*)(lnw + tid * 4);
  fl4 bb = *(const fl4*)(lnb + tid * 4);
  s16x4 o;
#pragma unroll
  for (int u = 0; u < 4; u++) o[u] = f2bf(d[u] * rstd * w[u] + bb[u]);
  *(s16x4*)(x + off) = o;
}

// ---------------- merged per-layer weight prep: 6 transposes + bias concat ----------------
struct Prep {
  const float *wq, *wk, *wv, *wo, *w1, *w2, *bq, *bk, *bv;
  short *qkvT, *woT, *w1T, *w2T;
  float* bias3;
};
__global__ void prep_kernel(Prep p) {
  int t = blockIdx.x;
  if (t >= 3072) {
    for (int k = threadIdx.x; k < QKVD; k += 256)
      p.bias3[k] = k < DIM ? p.bq[k] : (k < 2 * DIM ? p.bk[k - DIM] : p.bv[k - 2 * DIM]);
    return;
  }
  const float* in; short* out; int Kd, Nd, r0, c0;
  if (t < 1024) {
    int m = t >> 8, lt = t & 255;
    const float* srcs[4] = {p.wq, p.wk, p.wv, p.wo};
    short* dsts[4] = {p.qkvT, p.qkvT + (long)DIM * DIM, p.qkvT + (long)2 * DIM * DIM, p.woT};
    in = srcs[m]; out = dsts[m]; Kd = DIM; Nd = DIM;
    c0 = (lt & 15) * 64; r0 = (lt >> 4) * 64;
  } else if (t < 2048) {
    int lt = t - 1024; in = p.w1; out = p.w1T; Kd = DIM; Nd = FFN;
    c0 = (lt & 63) * 64; r0 = (lt >> 6) * 64;
  } else {
    int lt = t - 2048; in = p.w2; out = p.w2T; Kd = FFN; Nd = DIM;
    c0 = (lt & 15) * 64; r0 = (lt >> 4) * 64;
  }
  __shared__ float ts[64][65];
  int tid = threadIdx.x;
  int lr = tid >> 4, lc4 = (tid & 15) * 4;
#pragma unroll
  for (int i = 0; i < 4; i++) {
    fl4 v = *(const fl4*)(in + (long)(r0 + lr + i * 16) * Nd + c0 + lc4);
    ts[lr + i * 16][lc4] = v[0]; ts[lr + i * 16][lc4 + 1] = v[1];
    ts[lr + i * 16][lc4 + 2] = v[2]; ts[lr + i * 16][lc4 + 3] = v[3];
  }
  __syncthreads();
#pragma unroll
  for (int i = 0; i < 2; i++) {
    int oc = (tid >> 3) + i * 32, seg = tid & 7;
    bf16x8 o;
#pragma unroll
    for (int u = 0; u < 8; u++) o[u] = f2bf(ts[seg * 8 + u][oc]);
    *(bf16x8*)(out + (long)(c0 + oc) * Kd + r0 + seg * 8) = o;
  }
}

// ---------------- V transpose: qkv[s][2D+c] -> vt[c][s] ----------------
__global__ void transpose_v(const short* __restrict__ qkv, short* __restrict__ vt) {
  __shared__ short t[64][72];
  int s0 = blockIdx.x * 64, c0 = blockIdx.y * 64;
  int tid = threadIdx.x;
#pragma unroll
  for (int i = 0; i < 2; i++) {
    int ca = i * 256 + tid;
    int row = ca >> 3, cp = ca & 7;
    bf16x8 v = *(const bf16x8*)(qkv + (long)(s0 + row) * QKVD + 2 * DIM + c0 + cp * 8);
    *(bf16x8*)&t[row][cp * 8] = v;
  }
  __syncthreads();
#pragma unroll
  for (int i = 0; i < 2; i++) {
    int ca = i * 256 + tid;
    int crow = ca >> 3, sp = ca & 7;
    bf16x8 o;
#pragma unroll
    for (int u = 0; u < 8; u++) o[u] = t[sp * 8 + u][crow];
    *(bf16x8*)(vt + (long)(c0 + crow) * SEQ + s0 + sp * 8) = o;
  }
}

// ---------------- fp32 -> bf16 convert (lm_head) ----------------
__global__ void conv_bf16(const float* __restrict__ in, short* __restrict__ out, long n4) {
  long i = (long)blockIdx.x * blockDim.x + threadIdx.x;
  long stride = (long)gridDim.x * blockDim.x;
  for (; i < n4; i += stride) {
    fl4 v = *(const fl4*)(in + i * 4);
    s16x4 o;
    o[0] = f2bf(v[0]); o[1] = f2bf(v[1]); o[2] = f2bf(v[2]); o[3] = f2bf(v[3]);
    *(s16x4*)(out + i * 4) = o;
  }
}

// ---------------- gemm_small: 64x128 tile, BK=32, 4 waves (QKV/proj/FFN2) ----------------
template <bool GELU, bool BIAS, bool OUTBF16, int KS, bool XCDSWZ>
__global__ __launch_bounds__(256, 4) void gemm_small(
    const short* __restrict__ A, const short* __restrict__ Bt,
    const float* __restrict__ bias, void* __restrict__ Cout, int N, int Kfull) {
  __shared__ short lds[3][(64 + 128) * 32];  // 3 x 12KB
  const int tid = threadIdx.x, wid = tid >> 6, lane = tid & 63;
  const int l16 = lane & 15, lg = lane >> 4;
  int bx = blockIdx.x, by = blockIdx.y;
  if (XCDSWZ) {
    int gx = gridDim.x, nwg = gx * gridDim.y;
    int flat = by * gx + bx;
    int nf = (flat & 7) * (nwg >> 3) + (flat >> 3);
    bx = nf % gx; by = nf / gx;
  }
  const long m0 = (long)bx * 64, n0 = (long)by * 128;
  const int K = Kfull / KS;
  const int kbase = blockIdx.z * K;
  const int NT = K / 32;
  const int wm = wid >> 1, wn = wid & 1;

#define STG(t, b)                                                               \
  {                                                                             \
    short* As_ = lds[b];                                                        \
    short* Bs_ = lds[b] + 64 * 32;                                              \
    int kk_ = kbase + (t) * 32;                                                 \
    {                                                                           \
      int row_ = tid >> 2, cp_ = tid & 3, c_ = cp_ ^ ((row_ >> 1) & 3);         \
      gload_lds16(A + (m0 + row_) * (long)Kfull + kk_ + c_ * 8,                 \
                  As_ + (wid * 64) * 8);                                        \
    }                                                                           \
    _Pragma("unroll")                                                           \
    for (int i_ = 0; i_ < 2; i_++) {                                            \
      int ca_ = i_ * 256 + tid;                                                 \
      int row_ = ca_ >> 2, cp_ = ca_ & 3, c_ = cp_ ^ ((row_ >> 1) & 3);         \
      gload_lds16(Bt + (long)(n0 + row_) * Kfull + kk_ + c_ * 8,                \
                  Bs_ + (i_ * 256 + wid * 64) * 8);                             \
    }                                                                           \
  }

  f32x4 acc[2][4] = {};
  STG(0, 0);
  STG(1, 1);
  asm volatile("s_waitcnt vmcnt(3)" ::: "memory");
  __builtin_amdgcn_s_barrier();
  __builtin_amdgcn_sched_barrier(0);

  for (int t = 0; t < NT; t++) {
    const int b = t % 3;
    if (t + 2 < NT) STG(t + 2, (t + 2) % 3);
    const short* As = lds[b];
    const short* Bs = lds[b] + 64 * 32;
    bf16x8 af[2], bfr[4];
#pragma unroll
    for (int m = 0; m < 2; m++) {
      int row = wm * 32 + m * 16 + l16;
      af[m] = *(const bf16x8*)((const char*)As + row * 64 + ((lg ^ ((row >> 1) & 3)) * 16));
    }
#pragma unroll
    for (int n = 0; n < 4; n++) {
      int row = wn * 64 + n * 16 + l16;
      bfr[n] = *(const bf16x8*)((const char*)Bs + row * 64 + ((lg ^ ((row >> 1) & 3)) * 16));
    }
    __builtin_amdgcn_s_setprio(1);
#pragma unroll
    for (int m = 0; m < 2; m++)
#pragma unroll
      for (int n = 0; n < 4; n++)
        acc[m][n] = __builtin_amdgcn_mfma_f32_16x16x32_bf16(af[m], bfr[n], acc[m][n], 0, 0, 0);
    __builtin_amdgcn_s_setprio(0);
    if (t + 2 < NT) {
      asm volatile("s_waitcnt vmcnt(3)" ::: "memory");
    } else if (t + 1 < NT) {
      asm volatile("s_waitcnt vmcnt(0)" ::: "memory");
    }
    if (t + 1 < NT) {
      __builtin_amdgcn_s_barrier();
      __builtin_amdgcn_sched_barrier(0);
    }
  }
#undef STG

  const int lr4 = lg * 4;
  if (KS == 1) {
#pragma unroll
    for (int m = 0; m < 2; m++)
#pragma unroll
      for (int n = 0; n < 4; n++)
#pragma unroll
        for (int r = 0; r < 4; r++) {
          long row = m0 + wm * 32 + m * 16 + lr4 + r;
          long col = n0 + wn * 64 + n * 16 + l16;
          float v = acc[m][n][r];
          if (BIAS) v += bias[col];
          if (GELU) v = 0.5f * v * (1.f + erff(v * 0.70710678118f));
          if (OUTBF16) ((short*)Cout)[row * (long)N + col] = f2bf(v);
          else ((float*)Cout)[row * (long)N + col] = v;
        }
  } else {
    long M = (long)gridDim.x * 64;
    float* P = (float*)Cout + (long)blockIdx.z * M * N;
#pragma unroll
    for (int m = 0; m < 2; m++)
#pragma unroll
      for (int n = 0; n < 4; n++)
#pragma unroll
        for (int r = 0; r < 4; r++) {
          long row = m0 + wm * 32 + m * 16 + lr4 + r;
          long col = n0 + wn * 64 + n * 16 + l16;
          P[row * (long)N + col] = acc[m][n][r];
        }
  }
}

// ---------------- gemm4: 128x128, BK=32, 3 blocks/CU (FFN1) ----------------
template <bool GELU, bool BIAS, bool OUTBF16, bool XCDSWZ>
__global__ __launch_bounds__(256, 3) void gemm4(
    const short* __restrict__ A, const short* __restrict__ Bt,
    const float* __restrict__ bias, void* __restrict__ Cout, int N, int Kfull) {
  __shared__ short lds[3][(128 + 128) * 32];  // 3 x 16KB
  const int tid = threadIdx.x, wid = tid >> 6, lane = tid & 63;
  const int l16 = lane & 15, lg = lane >> 4;
  int bx = blockIdx.x, by = blockIdx.y;
  if (XCDSWZ) {
    int gx = gridDim.x, nwg = gx * gridDim.y;
    int flat = by * gx + bx;
    int nf = (flat & 7) * (nwg >> 3) + (flat >> 3);
    bx = nf % gx; by = nf / gx;
  }
  const long m0 = (long)bx * 128, n0 = (long)by * 128;
  const int NT = Kfull / 32;
  const int wr = (wid >> 1) * 64, wc = (wid & 1) * 64;

#define STAGE4(t, b)                                                            \
  {                                                                             \
    short* As_ = lds[b];                                                        \
    short* Bs_ = lds[b] + 128 * 32;                                             \
    int kk_ = (t) * 32;                                                         \
    _Pragma("unroll")                                                           \
    for (int i_ = 0; i_ < 2; i_++) {                                            \
      int ca_ = i_ * 256 + tid;                                                 \
      int row_ = ca_ >> 2, cp_ = ca_ & 3, c_ = cp_ ^ ((row_ >> 1) & 3);         \
      gload_lds16(A + (m0 + row_) * (long)Kfull + kk_ + c_ * 8,                 \
                  As_ + (i_ * 256 + wid * 64) * 8);                             \
    }                                                                           \
    _Pragma("unroll")                                                           \
    for (int i_ = 0; i_ < 2; i_++) {                                            \
      int ca_ = i_ * 256 + tid;                                                 \
      int row_ = ca_ >> 2, cp_ = ca_ & 3, c_ = cp_ ^ ((row_ >> 1) & 3);         \
      gload_lds16(Bt + (long)(n0 + row_) * Kfull + kk_ + c_ * 8,                \
                  Bs_ + (i_ * 256 + wid * 64) * 8);                             \
    }                                                                           \
  }

  f32x4 acc[4][4] = {};
  STAGE4(0, 0);
  STAGE4(1, 1);
  asm volatile("s_waitcnt vmcnt(4)" ::: "memory");
  __builtin_amdgcn_s_barrier();
  __builtin_amdgcn_sched_barrier(0);

  for (int t = 0; t < NT; t++) {
    const int b = t % 3;
    if (t + 2 < NT) STAGE4(t + 2, (t + 2) % 3);
    const short* As = lds[b];
    const short* Bs = lds[b] + 128 * 32;
    bf16x8 af[4], bfr[4];
#pragma unroll
    for (int m = 0; m < 4; m++) {
      int row = wr + m * 16 + l16;
      af[m] = *(const bf16x8*)((const char*)As + row * 64 + ((lg ^ ((row >> 1) & 3)) * 16));
    }
#pragma unroll
    for (int n = 0; n < 4; n++) {
      int row = wc + n * 16 + l16;
      bfr[n] = *(const bf16x8*)((const char*)Bs + row * 64 + ((lg ^ ((row >> 1) & 3)) * 16));
    }
    __builtin_amdgcn_s_setprio(1);
#pragma unroll
    for (int m = 0; m < 4; m++)
#pragma unroll
      for (int n = 0; n < 4; n++)
        acc[m][n] = __builtin_amdgcn_mfma_f32_16x16x32_bf16(af[m], bfr[n], acc[m][n], 0, 0, 0);
    __builtin_amdgcn_s_setprio(0);
    if (t + 2 < NT) {
      asm volatile("s_waitcnt vmcnt(4)" ::: "memory");
    } else if (t + 1 < NT) {
      asm volatile("s_waitcnt vmcnt(0)" ::: "memory");
    }
    if (t + 1 < NT) {
      __builtin_amdgcn_s_barrier();
      __builtin_amdgcn_sched_barrier(0);
    }
  }
#undef STAGE4

  const int lr4 = lg * 4;
#pragma unroll
  for (int m = 0; m < 4; m++)
#pragma unroll
    for (int n = 0; n < 4; n++)
#pragma unroll
      for (int r = 0; r < 4; r++) {
        long row = m0 + wr + m * 16 + lr4 + r;
        long col = n0 + wc + n * 16 + l16;
        float v = acc[m][n][r];
        if (BIAS) v += bias[col];
        if (GELU) v = 0.5f * v * (1.f + erff(v * 0.70710678118f));
        if (OUTBF16) ((short*)Cout)[row * (long)N + col] = f2bf(v);
        else ((float*)Cout)[row * (long)N + col] = v;
      }
}

// ---------------- gemm256p v2: persistent 8-phase 256x256 GEMM (lm_head) ----------------
// 256 blocks; block bid owns tiles f = f0 + 256t with f0 = (bid&7)*32 +
// (bid>>3): XCD x = bid&7 owns n-panel stripe [4x,4x+4) each walk step; the
// 8 same-XCD blocks sharing one panel make B L2-resident per XCD.
// Per K-step s (4 quadrant phases on buf s&1), stage step s+1 in ledger
// order B01(q0) B23(q1) A0A2(q2) A1A3(q3); waits: vmcnt(2) pre-q0 (B+A0A2
// resident, A1A3 in flight), vmcnt(4) pre-q2 (A1A3 resident). Epilogue at
// s%16==15 after the pre-q0 wait; stores drain under the next 2 phases.
__global__ __launch_bounds__(512, 1) void gemm256p(
    const short* __restrict__ A, const short* __restrict__ Bt,
    float* __restrict__ C, int N, int K, int totTiles) {
  __shared__ short ldsA[2][256 * 64];
  __shared__ short ldsB[2][256 * 64];
  const int tid = threadIdx.x, wid = tid >> 6, lane = tid & 63;
  const int l16 = lane & 15, lg = lane >> 4;
  const int wm = wid >> 2, wn = wid & 3;
  const int bid = blockIdx.x;
  const int f0 = (bid & 7) * 32 + (bid >> 3);
  const int nt = (totTiles - f0 + 255) / 256;
  const int TOT = nt * 16;  // K=1024 -> 16 K-steps per tile

  auto tileMN = [&](int ord, long& m0, long& n0) {
    int f = f0 + (ord << 8);
    m0 = (long)(f & 7) * 256;
    n0 = (long)(f >> 3) * 256;
  };
  auto SA = [&](int s, int r0) {
    long m0s, n0s; tileMN(s >> 4, m0s, n0s);
    int row = r0 + wid * 8 + (lane >> 3);
    int c = (lane & 7) ^ (row & 7);
    gload_lds16(A + (m0s + row) * (long)K + (s & 15) * 64 + c * 8,
                &ldsA[s & 1][(r0 + wid * 8) * 64]);
  };
  auto SB = [&](int s, int r0) {
    long m0s, n0s; tileMN(s >> 4, m0s, n0s);
    int row = r0 + wid * 8 + (lane >> 3);
    int c = (lane & 7) ^ (row & 7);
    int rowb = (int)n0s + row;
    if (rowb > N - 1) rowb = N - 1;
    gload_lds16(Bt + (long)rowb * K + (s & 15) * 64 + c * 8,
                &ldsB[s & 1][(r0 + wid * 8) * 64]);
  };

  f32x4 acc[8][4] = {};
  bf16x8 bfr[4][2];

  auto PH = [&](int b, int q) {
    bf16x8 af[2][2];
    if (q == 0) {
#pragma unroll
      for (int nf = 0; nf < 4; nf++) {
        int row = wn * 64 + nf * 16 + l16;
#pragma unroll
        for (int ks = 0; ks < 2; ks++)
          bfr[nf][ks] = *(const bf16x8*)((const char*)&ldsB[b][0] + row * 128 +
                                         (((ks * 4 + lg) ^ (row & 7)) * 16));
      }
    }
#pragma unroll
    for (int j = 0; j < 2; j++) {
      int row = wm * 128 + (q * 2 + j) * 16 + l16;
#pragma unroll
      for (int ks = 0; ks < 2; ks++)
        af[j][ks] = *(const bf16x8*)((const char*)&ldsA[b][0] + row * 128 +
                                     (((ks * 4 + lg) ^ (row & 7)) * 16));
    }
    __builtin_amdgcn_s_barrier();
    __builtin_amdgcn_s_setprio(1);
#pragma unroll
    for (int ks = 0; ks < 2; ks++)
#pragma unroll
      for (int j = 0; j < 2; j++)
#pragma unroll
        for (int nf = 0; nf < 4; nf++)
          acc[q * 2 + j][nf] =
              __builtin_amdgcn_mfma_f32_16x16x32_bf16(af[j][ks], bfr[nf][ks],
                                                      acc[q * 2 + j][nf], 0, 0, 0);
    __builtin_amdgcn_s_setprio(0);
  };

  // prologue: stage step 0 in ledger order; vmcnt(2) leaves A1A3(0) in flight
  SB(0, 0); SB(0, 64); SB(0, 128); SB(0, 192);
  SA(0, 0); SA(0, 128); SA(0, 64); SA(0, 192);
  asm volatile("s_waitcnt vmcnt(2)" ::: "memory");
  __builtin_amdgcn_s_barrier();

  for (int s = 0; s < TOT; s++) {
    const int b = s & 1;
    const bool stg = (s + 1) < TOT;
    // q0: compute | stage B01(s+1)
    if (stg) { SB(s + 1, 0); SB(s + 1, 64); }
    PH(b, 0);
    __builtin_amdgcn_s_barrier();
    // q1: compute | stage B23(s+1)
    if (stg) { SB(s + 1, 128); SB(s + 1, 192); }
    PH(b, 1);
    // pre-q2: A1A3(s) must be resident (staged at (s-1).q3 / prologue)
    if (stg) asm volatile("s_waitcnt vmcnt(4)" ::: "memory");
    else     asm volatile("s_waitcnt vmcnt(0)" ::: "memory");
    __builtin_amdgcn_s_barrier();
    // q2: compute | stage A0A2(s+1)
    if (stg) { SA(s + 1, 0); SA(s + 1, 128); }
    PH(b, 2);
    __builtin_amdgcn_s_barrier();
    // q3: compute | stage A1A3(s+1)
    if (stg) { SA(s + 1, 64); SA(s + 1, 192); }
    PH(b, 3);
    // pre-next-q0: B01,B23,A0A2 of s+1 resident; A1A3(s+1) stays in flight
    if (stg) asm volatile("s_waitcnt vmcnt(2)" ::: "memory");
    else     asm volatile("s_waitcnt vmcnt(0)" ::: "memory");
    __builtin_amdgcn_s_barrier();
    if ((s & 15) == 15) {  // output-tile boundary: store + zero acc
      long m0c, n0c; tileMN(s >> 4, m0c, n0c);
#pragma unroll
      for (int mf = 0; mf < 8; mf++)
#pragma unroll
        for (int nf = 0; nf < 4; nf++)
#pragma unroll
          for (int r = 0; r < 4; r++) {
            long row = m0c + wm * 128 + mf * 16 + lg * 4 + r;
            long col = n0c + wn * 64 + nf * 16 + l16;
            if (col < N) C[row * (long)N + col] = acc[mf][nf][r];
            acc[mf][nf][r] = 0.f;
          }
    }
  }
}

// ---------------- MFMA flash attention, KVBLK=128, dbuf staging + setprio ----------------
__global__ __launch_bounds__(256) void attn_mfma(const short* __restrict__ qkv,
                                                 const short* __restrict__ vtg,
                                                 short* __restrict__ Oa) {
  int hh = blockIdx.x, qb = blockIdx.y;
  int q0 = qb * 64;
  int tid = threadIdx.x, wv = tid >> 6, lane = tid & 63;
  int l16 = lane & 15, lg = lane >> 4;
  int hcol = hh * 64;
  __shared__ short Ks[2][KVB * 64];
  __shared__ short Vt[2][64 * KVB];
  __shared__ short Pl[4][16 * KVB];

  bf16x8 qf[2];
  {
    const short* qrow = qkv + (long)(q0 + wv * 16 + l16) * QKVD + hcol;
#pragma unroll
    for (int dc = 0; dc < 2; dc++) {
      bf16x8 t = *(const bf16x8*)(qrow + dc * 32 + lg * 8);
#pragma unroll
      for (int j = 0; j < 8; j++) t[j] = f2bf(bf2f(t[j]) * 0.125f);
      qf[dc] = t;
    }
  }
  f32x4 of[4] = {};
  float mrun[4], lrun[4];
#pragma unroll
  for (int r = 0; r < 4; r++) { mrun[r] = -3e38f; lrun[r] = 0.f; }

#define STAGEKV(kt_, b_)                                                        \
  {                                                                             \
    int k0_ = (kt_) * KVB;                                                      \
    _Pragma("unroll")                                                           \
    for (int i = 0; i < 4; i++) {                                               \
      int ca = i * 256 + tid;                                                   \
      int row = ca >> 3, cp = ca & 7, c = cp ^ (row & 7);                       \
      gload_lds16(qkv + (long)(k0_ + row) * QKVD + DIM + hcol + c * 8,          \
                  (short*)Ks[b_] + (i * 256 + wv * 64) * 8);                    \
    }                                                                           \
    _Pragma("unroll")                                                           \
    for (int i = 0; i < 4; i++) {                                               \
      int ca = i * 256 + tid;                                                   \
      int row = ca >> 4, cp = ca & 15, c = cp ^ (row & 7);                      \
      gload_lds16(vtg + (long)(hcol + row) * SEQ + k0_ + c * 8,                 \
                  (short*)Vt[b_] + (i * 256 + wv * 64) * 8);                    \
    }                                                                           \
  }

  int nt = qb / 2 + 1;
  STAGEKV(0, 0);
  asm volatile("s_waitcnt vmcnt(0)" ::: "memory");
  __builtin_amdgcn_s_barrier();

  for (int kt = 0; kt < nt; kt++) {
    const int cur = kt & 1;
    if (kt + 1 < nt) STAGEKV(kt + 1, cur ^ 1);
    int k0 = kt * KVB;

    f32x4 sacc[8] = {};
    __builtin_amdgcn_s_setprio(1);
#pragma unroll
    for (int kc = 0; kc < 8; kc++) {
      int row = kc * 16 + l16;
#pragma unroll
      for (int dc = 0; dc < 2; dc++) {
        bf16x8 kf = *(const bf16x8*)((const char*)Ks[cur] + row * 128 + (((dc * 4 + lg) ^ (row & 7)) * 16));
        sacc[kc] = __builtin_amdgcn_mfma_f32_16x16x32_bf16(qf[dc], kf, sacc[kc], 0, 0, 0);
      }
    }
    __builtin_amdgcn_s_setprio(0);

    float sv[8][4], pf[8][4];
#pragma unroll
    for (int kc = 0; kc < 8; kc++)
#pragma unroll
      for (int r = 0; r < 4; r++) sv[kc][r] = sacc[kc][r];
    if (kt == nt - 1) {
#pragma unroll
      for (int kc = 0; kc < 8; kc++)
#pragma unroll
        for (int r = 0; r < 4; r++) {
          int kg = k0 + kc * 16 + l16;
          int rg = q0 + wv * 16 + lg * 4 + r;
          if (kg > rg) sv[kc][r] = -3e38f;
        }
    }
    float corr[4];
#pragma unroll
    for (int r = 0; r < 4; r++) {
      float m01 = fmaxf(sv[0][r], sv[1][r]), m23 = fmaxf(sv[2][r], sv[3][r]);
      float m45 = fmaxf(sv[4][r], sv[5][r]), m67 = fmaxf(sv[6][r], sv[7][r]);
      float mt = fmaxf(fmaxf(m01, m23), fmaxf(m45, m67));
#pragma unroll
      for (int o = 8; o >= 1; o >>= 1) mt = fmaxf(mt, __shfl_xor(mt, o));
      float mn = fmaxf(mrun[r], mt);
      corr[r] = __expf(mrun[r] - mn);
      mrun[r] = mn;
      float ps = 0.f;
#pragma unroll
      for (int kc = 0; kc < 8; kc++) {
        float p = __expf(sv[kc][r] - mn);
        pf[kc][r] = p;
        ps += p;
      }
#pragma unroll
      for (int o = 8; o >= 1; o >>= 1) ps += __shfl_xor(ps, o);
      lrun[r] = lrun[r] * corr[r] + ps;
    }
#pragma unroll
    for (int c = 0; c < 4; c++)
#pragma unroll
      for (int r = 0; r < 4; r++) of[c][r] *= corr[r];
#pragma unroll
    for (int kc = 0; kc < 8; kc++)
#pragma unroll
      for (int r = 0; r < 4; r++) {
        int row = lg * 4 + r, col = kc * 16 + l16;
        int chunk = col >> 3;
        *(short*)((char*)Pl[wv] + row * 256 + ((chunk ^ (row & 7)) * 16) + (col & 7) * 2) = f2bf(pf[kc][r]);
      }
    bf16x8 pfr[4];
#pragma unroll
    for (int kc2 = 0; kc2 < 4; kc2++) {
      int cl = kc2 * 4 + lg;
      pfr[kc2] = *(const bf16x8*)((const char*)Pl[wv] + l16 * 256 + ((cl ^ (l16 & 7)) * 16));
    }
    __builtin_amdgcn_s_setprio(1);
#pragma unroll
    for (int c = 0; c < 4; c++)
#pragma unroll
      for (int kc2 = 0; kc2 < 4; kc2++) {
        int vrow = c * 16 + l16;
        int cl = kc2 * 4 + lg;
        bf16x8 vf = *(const bf16x8*)((const char*)Vt[cur] + vrow * 256 + ((cl ^ (vrow & 7)) * 16));
        of[c] = __builtin_amdgcn_mfma_f32_16x16x32_bf16(pfr[kc2], vf, of[c], 0, 0, 0);
      }
    __builtin_amdgcn_s_setprio(0);
    if (kt + 1 < nt) {
      asm volatile("s_waitcnt vmcnt(0)" ::: "memory");
      __builtin_amdgcn_s_barrier();
      __builtin_amdgcn_sched_barrier(0);
    }
  }
#undef STAGEKV
#pragma unroll
  for (int c = 0; c < 4; c++)
#pragma unroll
    for (int r = 0; r < 4; r++) {
      int rowg = q0 + wv * 16 + lg * 4 + r;
      int colg = hcol + c * 16 + l16;
      Oa[(long)rowg * DIM + colg] = f2bf(of[c][r] / lrun[r]);
    }
}

// ---------------- orchestration ----------------
extern "C" void kernel_launch(void* const* d_in, const int* in_sizes, int n_in,
                              void* d_out, int out_size, void* d_ws, size_t ws_size,
                              hipStream_t stream) {
  const int* ids = (const int*)d_in[0];
  const float* tok = (const float*)d_in[1];
  const float* pos = (const float*)d_in[2];
  const float* Wq = (const float*)d_in[3];
  const float* bq = (const float*)d_in[4];
  const float* Wk = (const float*)d_in[5];
  const float* bk = (const float*)d_in[6];
  const float* Wv = (const float*)d_in[7];
  const float* bv = (const float*)d_in[8];
  const float* Wo = (const float*)d_in[9];
  const float* bo = (const float*)d_in[10];
  const float* W1 = (const float*)d_in[11];
  const float* b1 = (const float*)d_in[12];
  const float* W2 = (const float*)d_in[13];
  const float* b2 = (const float*)d_in[14];
  const float* ln1w = (const float*)d_in[15];
  const float* ln1b = (const float*)d_in[16];
  const float* ln2w = (const float*)d_in[17];
  const float* ln2b = (const float*)d_in[18];
  const float* lnfw = (const float*)d_in[19];
  const float* lnfb = (const float*)d_in[20];
  const float* lmh = (const float*)d_in[21];
  float* out = (float*)d_out;

  char* wsb = (char*)d_ws;
  float* h = (float*)wsb;                           // 8 MB fp32 residual
  short* x = (short*)(wsb + 8388608);               // 4 MB bf16 LN out
  char* big = wsb + 8388608 + 4194304;
  short* qkv  = (short*)big;                        // 12 MB   [S][3072]
  short* a    = (short*)(big + 12582912);           // 4 MB    [S][1024]
  short* vt   = (short*)(big + 16777216);           // 4 MB    [1024][S]
  short* fbuf = (short*)(big + 20971520);           // 16 MB   [S][4096]
  float* pproj = (float*)fbuf;                      // proj partials: 2x8MB
  float* pffn2 = (float*)big;                       // ffn2 partials: 2x8MB (qkv+a free)
  char* wdyn = big + 37748736;
  short* wqkvT = (short*)wdyn;                      // 6 MB  [3072][1024]
  short* woT   = (short*)(wdyn + 6291456);          // 2 MB  [1024][1024]
  short* w1T   = (short*)(wdyn + 8388608);          // 8 MB  [4096][1024]
  short* w2T   = (short*)(wdyn + 16777216);         // 8 MB  [1024][4096]
  float* bias3 = (float*)(wdyn + 25165824);         // 12 KB
  short* lmhB = (short*)big;                        // 103 MB, reused after layers

  embed_kernel<<<(SEQ * DIM + 255) / 256, 256, 0, stream>>>(ids, tok, pos, h);
  ln_kernel<<<SEQ, 256, 0, stream>>>(h, ln1w, ln1b, x);  // layer 0 ln1

  dim3 gQKV(SEQ / 64, QKVD / 128);                  // 32 x 24 = 768
  dim3 gPROJ(SEQ / 64, DIM / 128, 2);               // 32 x 8 x 2 = 512
  dim3 gFFN1(SEQ / 128, FFN / 128);                 // 16 x 32 = 512
  dim3 gFFN2(SEQ / 64, DIM / 128, 2);               // 32 x 8 x 2 = 512

  for (int l = 0; l < NLAYER; l++) {
    Prep p;
    p.wq = Wq + (long)l * DIM * DIM; p.wk = Wk + (long)l * DIM * DIM;
    p.wv = Wv + (long)l * DIM * DIM; p.wo = Wo + (long)l * DIM * DIM;
    p.w1 = W1 + (long)l * DIM * FFN; p.w2 = W2 + (long)l * FFN * DIM;
    p.bq = bq + (long)l * DIM; p.bk = bk + (long)l * DIM; p.bv = bv + (long)l * DIM;
    p.qkvT = wqkvT; p.woT = woT; p.w1T = w1T; p.w2T = w2T; p.bias3 = bias3;
    prep_kernel<<<3073, 256, 0, stream>>>(p);

    gemm_small<false, true, true, 1, true><<<gQKV, 256, 0, stream>>>(x, wqkvT, bias3, qkv, QKVD, DIM);
    transpose_v<<<dim3(SEQ / 64, DIM / 64), 256, 0, stream>>>(qkv, vt);
    attn_mfma<<<dim3(NHEAD, SEQ / 64), 256, 0, stream>>>(qkv, vt, a);
    gemm_small<false, false, false, 2, true><<<gPROJ, 256, 0, stream>>>(a, woT, nullptr, pproj, DIM, DIM);
    reduce_ln<<<SEQ, 256, 0, stream>>>(pproj, bo + (long)l * DIM,
                                       ln2w + (long)l * DIM, ln2b + (long)l * DIM, h, x);
    gemm4<true, true, true, true><<<gFFN1, 256, 0, stream>>>(x, w1T, b1 + (long)l * FFN, fbuf, FFN, DIM);
    gemm_small<false, false, false, 2, true><<<gFFN2, 256, 0, stream>>>(fbuf, w2T, nullptr, pffn2, DIM, FFN);
    const float* nw = (l < NLAYER - 1) ? ln1w + (long)(l + 1) * DIM : lnfw;
    const float* nb = (l < NLAYER - 1) ? ln1b + (long)(l + 1) * DIM : lnfb;
    reduce_ln<<<SEQ, 256, 0, stream>>>(pffn2, b2 + (long)l * DIM, nw, nb, h, x);
  }

  conv_bf16<<<2048, 256, 0, stream>>>(lmh, lmhB, (long)VOCAB * DIM / 4);
  gemm256p<<<dim3(256), 512, 0, stream>>>(x, lmhB, out, VOCAB, DIM,
                                          (SEQ / 256) * ((VOCAB + 255) / 256));
}

// Round 11
// 1115.551 us; speedup vs baseline: 1.0324x; 1.0324x over previous
//
#include <hip/hip_runtime.h>
#include <math.h>
#include <stdint.h>

// GPT fwd, L=4 D=1024 H=16 HS=64 F=4096 V=50257 S=2048.
// Round 11: gemm256p v3 — XCD tile map (R10's fetch win) + deep-slack
// single-wait ledger derived from LDS death times (B dead after q0,
// A0A2 after q1, A1A3 after q3): stage q0:A1A3(s+1) q1:B01(s+2)
// q2:B23(s+2) q3:A0A2(s+2), one vmcnt(6) per step. Slack 4-7 phases.
// All other kernels identical to R9 (1118 us).

#define SEQ 2048
#define DIM 1024
#define NHEAD 16
#define FFN 4096
#define VOCAB 50257
#define NLAYER 4
#define LNEPS 1e-5f
#define QKVD 3072
#define KVB 128

using bf16x8 = __attribute__((ext_vector_type(8))) short;
using s16x4  = __attribute__((ext_vector_type(4))) short;
using f32x4  = __attribute__((ext_vector_type(4))) float;
using fl4    = __attribute__((ext_vector_type(4))) float;

static __device__ __forceinline__ short f2bf(float f) {
  uint32_t u = __float_as_uint(f);
  u = (u + 0x7fffu + ((u >> 16) & 1u)) >> 16;
  return (short)u;
}
static __device__ __forceinline__ float bf2f(short s) {
  return __uint_as_float(((uint32_t)(uint16_t)s) << 16);
}
static __device__ __forceinline__ void gload_lds16(const void* g, void* l) {
  __builtin_amdgcn_global_load_lds((const __attribute__((address_space(1))) void*)g,
                                   (__attribute__((address_space(3))) void*)l, 16, 0, 0);
}

// ---------------- embedding (fp32 h) ----------------
__global__ void embed_kernel(const int* __restrict__ ids,
                             const float* __restrict__ tok,
                             const float* __restrict__ pos,
                             float* __restrict__ h) {
  int i = blockIdx.x * blockDim.x + threadIdx.x;
  if (i < SEQ * DIM) {
    int s = i / DIM, d = i % DIM;
    h[i] = tok[(long)ids[s] * DIM + d] + pos[i];
  }
}

// ---------------- layernorm: fp32 in -> bf16 out (layer0 ln1 only) ----------------
__global__ void ln_kernel(const float* __restrict__ x, const float* __restrict__ w,
                          const float* __restrict__ b, short* __restrict__ y) {
  int row = blockIdx.x;
  const float* xr = x + (long)row * DIM;
  short* yr = y + (long)row * DIM;
  int tid = threadIdx.x;
  float v0 = xr[tid], v1 = xr[tid + 256], v2 = xr[tid + 512], v3 = xr[tid + 768];
  __shared__ float red[8];
  float s = v0 + v1 + v2 + v3;
#pragma unroll
  for (int o = 32; o >= 1; o >>= 1) s += __shfl_xor(s, o);
  if ((tid & 63) == 0) red[tid >> 6] = s;
  __syncthreads();
  float mean = (red[0] + red[1] + red[2] + red[3]) * (1.f / DIM);
  float d0 = v0 - mean, d1 = v1 - mean, d2 = v2 - mean, d3 = v3 - mean;
  float q = d0 * d0 + d1 * d1 + d2 * d2 + d3 * d3;
#pragma unroll
  for (int o = 32; o >= 1; o >>= 1) q += __shfl_xor(q, o);
  if ((tid & 63) == 0) red[4 + (tid >> 6)] = q;
  __syncthreads();
  float var = (red[4] + red[5] + red[6] + red[7]) * (1.f / DIM);
  float rstd = rsqrtf(var + LNEPS);
  yr[tid]       = f2bf(d0 * rstd * w[tid] + b[tid]);
  yr[tid + 256] = f2bf(d1 * rstd * w[tid + 256] + b[tid + 256]);
  yr[tid + 512] = f2bf(d2 * rstd * w[tid + 512] + b[tid + 512]);
  yr[tid + 768] = f2bf(d3 * rstd * w[tid + 768] + b[tid + 768]);
}

// ---------------- fused: h += bias + part0 + part1; x = LN(h) bf16 ----------------
__global__ void reduce_ln(const float* __restrict__ part, const float* __restrict__ bias,
                          const float* __restrict__ lnw, const float* __restrict__ lnb,
                          float* __restrict__ h, short* __restrict__ x) {
  const long MN = (long)SEQ * DIM;
  int row = blockIdx.x, tid = threadIdx.x;
  long off = (long)row * DIM + tid * 4;
  fl4 hv = *(const fl4*)(h + off);
  fl4 p0 = *(const fl4*)(part + off);
  fl4 p1 = *(const fl4*)(part + MN + off);
  fl4 bv = *(const fl4*)(bias + tid * 4);
  float v[4];
#pragma unroll
  for (int u = 0; u < 4; u++) v[u] = hv[u] + p0[u] + p1[u] + bv[u];
  __shared__ float red[8];
  float s = v[0] + v[1] + v[2] + v[3];
#pragma unroll
  for (int o = 32; o >= 1; o >>= 1) s += __shfl_xor(s, o);
  if ((tid & 63) == 0) red[tid >> 6] = s;
  __syncthreads();
  float mean = (red[0] + red[1] + red[2] + red[3]) * (1.f / DIM);
  float d[4], q = 0.f;
#pragma unroll
  for (int u = 0; u < 4; u++) { d[u] = v[u] - mean; q += d[u] * d[u]; }
#pragma unroll
  for (int o = 32; o >= 1; o >>= 1) q += __shfl_xor(q, o);
  if ((tid & 63) == 0) red[4 + (tid >> 6)] = q;
  fl4 hw; hw[0] = v[0]; hw[1] = v[1]; hw[2] = v[2]; hw[3] = v[3];
  *(fl4*)(h + off) = hw;
  __syncthreads();
  float var = (red[4] + red[5] + red[6] + red[7]) * (1.f / DIM);
  float rstd = rsqrtf(var + LNEPS);
  fl4 w = *(const fl4*)(lnw + tid * 4);
  fl4 bb = *(const fl4*)(lnb + tid * 4);
  s16x4 o;
#pragma unroll
  for (int u = 0; u < 4; u++) o[u] = f2bf(d[u] * rstd * w[u] + bb[u]);
  *(s16x4*)(x + off) = o;
}

// ---------------- merged per-layer weight prep: 6 transposes + bias concat ----------------
struct Prep {
  const float *wq, *wk, *wv, *wo, *w1, *w2, *bq, *bk, *bv;
  short *qkvT, *woT, *w1T, *w2T;
  float* bias3;
};
__global__ void prep_kernel(Prep p) {
  int t = blockIdx.x;
  if (t >= 3072) {
    for (int k = threadIdx.x; k < QKVD; k += 256)
      p.bias3[k] = k < DIM ? p.bq[k] : (k < 2 * DIM ? p.bk[k - DIM] : p.bv[k - 2 * DIM]);
    return;
  }
  const float* in; short* out; int Kd, Nd, r0, c0;
  if (t < 1024) {
    int m = t >> 8, lt = t & 255;
    const float* srcs[4] = {p.wq, p.wk, p.wv, p.wo};
    short* dsts[4] = {p.qkvT, p.qkvT + (long)DIM * DIM, p.qkvT + (long)2 * DIM * DIM, p.woT};
    in = srcs[m]; out = dsts[m]; Kd = DIM; Nd = DIM;
    c0 = (lt & 15) * 64; r0 = (lt >> 4) * 64;
  } else if (t < 2048) {
    int lt = t - 1024; in = p.w1; out = p.w1T; Kd = DIM; Nd = FFN;
    c0 = (lt & 63) * 64; r0 = (lt >> 6) * 64;
  } else {
    int lt = t - 2048; in = p.w2; out = p.w2T; Kd = FFN; Nd = DIM;
    c0 = (lt & 15) * 64; r0 = (lt >> 4) * 64;
  }
  __shared__ float ts[64][65];
  int tid = threadIdx.x;
  int lr = tid >> 4, lc4 = (tid & 15) * 4;
#pragma unroll
  for (int i = 0; i < 4; i++) {
    fl4 v = *(const fl4*)(in + (long)(r0 + lr + i * 16) * Nd + c0 + lc4);
    ts[lr + i * 16][lc4] = v[0]; ts[lr + i * 16][lc4 + 1] = v[1];
    ts[lr + i * 16][lc4 + 2] = v[2]; ts[lr + i * 16][lc4 + 3] = v[3];
  }
  __syncthreads();
#pragma unroll
  for (int i = 0; i < 2; i++) {
    int oc = (tid >> 3) + i * 32, seg = tid & 7;
    bf16x8 o;
#pragma unroll
    for (int u = 0; u < 8; u++) o[u] = f2bf(ts[seg * 8 + u][oc]);
    *(bf16x8*)(out + (long)(c0 + oc) * Kd + r0 + seg * 8) = o;
  }
}

// ---------------- V transpose: qkv[s][2D+c] -> vt[c][s] ----------------
__global__ void transpose_v(const short* __restrict__ qkv, short* __restrict__ vt) {
  __shared__ short t[64][72];
  int s0 = blockIdx.x * 64, c0 = blockIdx.y * 64;
  int tid = threadIdx.x;
#pragma unroll
  for (int i = 0; i < 2; i++) {
    int ca = i * 256 + tid;
    int row = ca >> 3, cp = ca & 7;
    bf16x8 v = *(const bf16x8*)(qkv + (long)(s0 + row) * QKVD + 2 * DIM + c0 + cp * 8);
    *(bf16x8*)&t[row][cp * 8] = v;
  }
  __syncthreads();
#pragma unroll
  for (int i = 0; i < 2; i++) {
    int ca = i * 256 + tid;
    int crow = ca >> 3, sp = ca & 7;
    bf16x8 o;
#pragma unroll
    for (int u = 0; u < 8; u++) o[u] = t[sp * 8 + u][crow];
    *(bf16x8*)(vt + (long)(c0 + crow) * SEQ + s0 + sp * 8) = o;
  }
}

// ---------------- fp32 -> bf16 convert (lm_head) ----------------
__global__ void conv_bf16(const float* __restrict__ in, short* __restrict__ out, long n4) {
  long i = (long)blockIdx.x * blockDim.x + threadIdx.x;
  long stride = (long)gridDim.x * blockDim.x;
  for (; i < n4; i += stride) {
    fl4 v = *(const fl4*)(in + i * 4);
    s16x4 o;
    o[0] = f2bf(v[0]); o[1] = f2bf(v[1]); o[2] = f2bf(v[2]); o[3] = f2bf(v[3]);
    *(s16x4*)(out + i * 4) = o;
  }
}

// ---------------- gemm_small: 64x128 tile, BK=32, 4 waves (QKV/proj/FFN2) ----------------
template <bool GELU, bool BIAS, bool OUTBF16, int KS, bool XCDSWZ>
__global__ __launch_bounds__(256, 4) void gemm_small(
    const short* __restrict__ A, const short* __restrict__ Bt,
    const float* __restrict__ bias, void* __restrict__ Cout, int N, int Kfull) {
  __shared__ short lds[3][(64 + 128) * 32];  // 3 x 12KB
  const int tid = threadIdx.x, wid = tid >> 6, lane = tid & 63;
  const int l16 = lane & 15, lg = lane >> 4;
  int bx = blockIdx.x, by = blockIdx.y;
  if (XCDSWZ) {
    int gx = gridDim.x, nwg = gx * gridDim.y;
    int flat = by * gx + bx;
    int nf = (flat & 7) * (nwg >> 3) + (flat >> 3);
    bx = nf % gx; by = nf / gx;
  }
  const long m0 = (long)bx * 64, n0 = (long)by * 128;
  const int K = Kfull / KS;
  const int kbase = blockIdx.z * K;
  const int NT = K / 32;
  const int wm = wid >> 1, wn = wid & 1;

#define STG(t, b)                                                               \
  {                                                                             \
    short* As_ = lds[b];                                                        \
    short* Bs_ = lds[b] + 64 * 32;                                              \
    int kk_ = kbase + (t) * 32;                                                 \
    {                                                                           \
      int row_ = tid >> 2, cp_ = tid & 3, c_ = cp_ ^ ((row_ >> 1) & 3);         \
      gload_lds16(A + (m0 + row_) * (long)Kfull + kk_ + c_ * 8,                 \
                  As_ + (wid * 64) * 8);                                        \
    }                                                                           \
    _Pragma("unroll")                                                           \
    for (int i_ = 0; i_ < 2; i_++) {                                            \
      int ca_ = i_ * 256 + tid;                                                 \
      int row_ = ca_ >> 2, cp_ = ca_ & 3, c_ = cp_ ^ ((row_ >> 1) & 3);         \
      gload_lds16(Bt + (long)(n0 + row_) * Kfull + kk_ + c_ * 8,                \
                  Bs_ + (i_ * 256 + wid * 64) * 8);                             \
    }                                                                           \
  }

  f32x4 acc[2][4] = {};
  STG(0, 0);
  STG(1, 1);
  asm volatile("s_waitcnt vmcnt(3)" ::: "memory");
  __builtin_amdgcn_s_barrier();
  __builtin_amdgcn_sched_barrier(0);

  for (int t = 0; t < NT; t++) {
    const int b = t % 3;
    if (t + 2 < NT) STG(t + 2, (t + 2) % 3);
    const short* As = lds[b];
    const short* Bs = lds[b] + 64 * 32;
    bf16x8 af[2], bfr[4];
#pragma unroll
    for (int m = 0; m < 2; m++) {
      int row = wm * 32 + m * 16 + l16;
      af[m] = *(const bf16x8*)((const char*)As + row * 64 + ((lg ^ ((row >> 1) & 3)) * 16));
    }
#pragma unroll
    for (int n = 0; n < 4; n++) {
      int row = wn * 64 + n * 16 + l16;
      bfr[n] = *(const bf16x8*)((const char*)Bs + row * 64 + ((lg ^ ((row >> 1) & 3)) * 16));
    }
    __builtin_amdgcn_s_setprio(1);
#pragma unroll
    for (int m = 0; m < 2; m++)
#pragma unroll
      for (int n = 0; n < 4; n++)
        acc[m][n] = __builtin_amdgcn_mfma_f32_16x16x32_bf16(af[m], bfr[n], acc[m][n], 0, 0, 0);
    __builtin_amdgcn_s_setprio(0);
    if (t + 2 < NT) {
      asm volatile("s_waitcnt vmcnt(3)" ::: "memory");
    } else if (t + 1 < NT) {
      asm volatile("s_waitcnt vmcnt(0)" ::: "memory");
    }
    if (t + 1 < NT) {
      __builtin_amdgcn_s_barrier();
      __builtin_amdgcn_sched_barrier(0);
    }
  }
#undef STG

  const int lr4 = lg * 4;
  if (KS == 1) {
#pragma unroll
    for (int m = 0; m < 2; m++)
#pragma unroll
      for (int n = 0; n < 4; n++)
#pragma unroll
        for (int r = 0; r < 4; r++) {
          long row = m0 + wm * 32 + m * 16 + lr4 + r;
          long col = n0 + wn * 64 + n * 16 + l16;
          float v = acc[m][n][r];
          if (BIAS) v += bias[col];
          if (GELU) v = 0.5f * v * (1.f + erff(v * 0.70710678118f));
          if (OUTBF16) ((short*)Cout)[row * (long)N + col] = f2bf(v);
          else ((float*)Cout)[row * (long)N + col] = v;
        }
  } else {
    long M = (long)gridDim.x * 64;
    float* P = (float*)Cout + (long)blockIdx.z * M * N;
#pragma unroll
    for (int m = 0; m < 2; m++)
#pragma unroll
      for (int n = 0; n < 4; n++)
#pragma unroll
        for (int r = 0; r < 4; r++) {
          long row = m0 + wm * 32 + m * 16 + lr4 + r;
          long col = n0 + wn * 64 + n * 16 + l16;
          P[row * (long)N + col] = acc[m][n][r];
        }
  }
}

// ---------------- gemm4: 128x128, BK=32, 3 blocks/CU (FFN1) ----------------
template <bool GELU, bool BIAS, bool OUTBF16, bool XCDSWZ>
__global__ __launch_bounds__(256, 3) void gemm4(
    const short* __restrict__ A, const short* __restrict__ Bt,
    const float* __restrict__ bias, void* __restrict__ Cout, int N, int Kfull) {
  __shared__ short lds[3][(128 + 128) * 32];  // 3 x 16KB
  const int tid = threadIdx.x, wid = tid >> 6, lane = tid & 63;
  const int l16 = lane & 15, lg = lane >> 4;
  int bx = blockIdx.x, by = blockIdx.y;
  if (XCDSWZ) {
    int gx = gridDim.x, nwg = gx * gridDim.y;
    int flat = by * gx + bx;
    int nf = (flat & 7) * (nwg >> 3) + (flat >> 3);
    bx = nf % gx; by = nf / gx;
  }
  const long m0 = (long)bx * 128, n0 = (long)by * 128;
  const int NT = Kfull / 32;
  const int wr = (wid >> 1) * 64, wc = (wid & 1) * 64;

#define STAGE4(t, b)                                                            \
  {                                                                             \
    short* As_ = lds[b];                                                        \
    short* Bs_ = lds[b] + 128 * 32;                                             \
    int kk_ = (t) * 32;                                                         \
    _Pragma("unroll")                                                           \
    for (int i_ = 0; i_ < 2; i_++) {                                            \
      int ca_ = i_ * 256 + tid;                                                 \
      int row_ = ca_ >> 2, cp_ = ca_ & 3, c_ = cp_ ^ ((row_ >> 1) & 3);         \
      gload_lds16(A + (m0 + row_) * (long)Kfull + kk_ + c_ * 8,                 \
                  As_ + (i_ * 256 + wid * 64) * 8);                             \
    }                                                                           \
    _Pragma("unroll")                                                           \
    for (int i_ = 0; i_ < 2; i_++) {                                            \
      int ca_ = i_ * 256 + tid;                                                 \
      int row_ = ca_ >> 2, cp_ = ca_ & 3, c_ = cp_ ^ ((row_ >> 1) & 3);         \
      gload_lds16(Bt + (long)(n0 + row_) * Kfull + kk_ + c_ * 8,                \
                  Bs_ + (i_ * 256 + wid * 64) * 8);                             \
    }                                                                           \
  }

  f32x4 acc[4][4] = {};
  STAGE4(0, 0);
  STAGE4(1, 1);
  asm volatile("s_waitcnt vmcnt(4)" ::: "memory");
  __builtin_amdgcn_s_barrier();
  __builtin_amdgcn_sched_barrier(0);

  for (int t = 0; t < NT; t++) {
    const int b = t % 3;
    if (t + 2 < NT) STAGE4(t + 2, (t + 2) % 3);
    const short* As = lds[b];
    const short* Bs = lds[b] + 128 * 32;
    bf16x8 af[4], bfr[4];
#pragma unroll
    for (int m = 0; m < 4; m++) {
      int row = wr + m * 16 + l16;
      af[m] = *(const bf16x8*)((const char*)As + row * 64 + ((lg ^ ((row >> 1) & 3)) * 16));
    }
#pragma unroll
    for (int n = 0; n < 4; n++) {
      int row = wc + n * 16 + l16;
      bfr[n] = *(const bf16x8*)((const char*)Bs + row * 64 + ((lg ^ ((row >> 1) & 3)) * 16));
    }
    __builtin_amdgcn_s_setprio(1);
#pragma unroll
    for (int m = 0; m < 4; m++)
#pragma unroll
      for (int n = 0; n < 4; n++)
        acc[m][n] = __builtin_amdgcn_mfma_f32_16x16x32_bf16(af[m], bfr[n], acc[m][n], 0, 0, 0);
    __builtin_amdgcn_s_setprio(0);
    if (t + 2 < NT) {
      asm volatile("s_waitcnt vmcnt(4)" ::: "memory");
    } else if (t + 1 < NT) {
      asm volatile("s_waitcnt vmcnt(0)" ::: "memory");
    }
    if (t + 1 < NT) {
      __builtin_amdgcn_s_barrier();
      __builtin_amdgcn_sched_barrier(0);
    }
  }
#undef STAGE4

  const int lr4 = lg * 4;
#pragma unroll
  for (int m = 0; m < 4; m++)
#pragma unroll
    for (int n = 0; n < 4; n++)
#pragma unroll
      for (int r = 0; r < 4; r++) {
        long row = m0 + wr + m * 16 + lr4 + r;
        long col = n0 + wc + n * 16 + l16;
        float v = acc[m][n][r];
        if (BIAS) v += bias[col];
        if (GELU) v = 0.5f * v * (1.f + erff(v * 0.70710678118f));
        if (OUTBF16) ((short*)Cout)[row * (long)N + col] = f2bf(v);
        else ((float*)Cout)[row * (long)N + col] = v;
      }
}

// ---------------- gemm256p v3: persistent 8-phase 256x256 GEMM (lm_head) ----------------
// XCD map: f0 = (bid&7)*32 + (bid>>3) — XCD x owns contiguous n-panel
// stripe; 8 same-XCD blocks share each B panel (FETCH 172MB, R10-proven).
// Deep-slack ledger from LDS death times (B dead after q0 [regs], A0A2
// after q1, A1A3 after q3): per step s (buf b=s&1):
//   q0: stage A1A3(s+1)->buf(s^1) | q1: B01(s+2)->buf(s)
//   q2: B23(s+2)                  | q3: A0A2(s+2)
// ONE vmcnt(6) per step (end of q3): retires A1A3(s+1) and older, leaves
// tile s+2's 6 loads in flight. Slack: B01 7ph, B23 6ph, A0A2 5ph, A1A3
// 4ph — all >= HBM latency. Epilogue at s%16==15 after the wait+barrier.
__global__ __launch_bounds__(512, 1) void gemm256p(
    const short* __restrict__ A, const short* __restrict__ Bt,
    float* __restrict__ C, int N, int K, int totTiles) {
  __shared__ short ldsA[2][256 * 64];
  __shared__ short ldsB[2][256 * 64];
  const int tid = threadIdx.x, wid = tid >> 6, lane = tid & 63;
  const int l16 = lane & 15, lg = lane >> 4;
  const int wm = wid >> 2, wn = wid & 3;
  const int bid = blockIdx.x;
  const int f0 = (bid & 7) * 32 + (bid >> 3);
  const int nt = (totTiles - f0 + 255) / 256;
  const int TOT = nt * 16;  // K=1024 -> 16 K-steps per tile

  auto tileMN = [&](int ord, long& m0, long& n0) {
    int f = f0 + (ord << 8);
    m0 = (long)(f & 7) * 256;
    n0 = (long)(f >> 3) * 256;
  };
  auto SA = [&](int s, int r0) {
    long m0s, n0s; tileMN(s >> 4, m0s, n0s);
    int row = r0 + wid * 8 + (lane >> 3);
    int c = (lane & 7) ^ (row & 7);
    gload_lds16(A + (m0s + row) * (long)K + (s & 15) * 64 + c * 8,
                &ldsA[s & 1][(r0 + wid * 8) * 64]);
  };
  auto SB = [&](int s, int r0) {
    long m0s, n0s; tileMN(s >> 4, m0s, n0s);
    int row = r0 + wid * 8 + (lane >> 3);
    int c = (lane & 7) ^ (row & 7);
    int rowb = (int)n0s + row;
    if (rowb > N - 1) rowb = N - 1;
    gload_lds16(Bt + (long)rowb * K + (s & 15) * 64 + c * 8,
                &ldsB[s & 1][(r0 + wid * 8) * 64]);
  };

  f32x4 acc[8][4] = {};
  bf16x8 bfr[4][2];

  auto PH = [&](int b, int q) {
    bf16x8 af[2][2];
    if (q == 0) {
#pragma unroll
      for (int nf = 0; nf < 4; nf++) {
        int row = wn * 64 + nf * 16 + l16;
#pragma unroll
        for (int ks = 0; ks < 2; ks++)
          bfr[nf][ks] = *(const bf16x8*)((const char*)&ldsB[b][0] + row * 128 +
                                         (((ks * 4 + lg) ^ (row & 7)) * 16));
      }
    }
#pragma unroll
    for (int j = 0; j < 2; j++) {
      int row = wm * 128 + (q * 2 + j) * 16 + l16;
#pragma unroll
      for (int ks = 0; ks < 2; ks++)
        af[j][ks] = *(const bf16x8*)((const char*)&ldsA[b][0] + row * 128 +
                                     (((ks * 4 + lg) ^ (row & 7)) * 16));
    }
    __builtin_amdgcn_s_barrier();
    __builtin_amdgcn_s_setprio(1);
#pragma unroll
    for (int ks = 0; ks < 2; ks++)
#pragma unroll
      for (int j = 0; j < 2; j++)
#pragma unroll
        for (int nf = 0; nf < 4; nf++)
          acc[q * 2 + j][nf] =
              __builtin_amdgcn_mfma_f32_16x16x32_bf16(af[j][ks], bfr[nf][ks],
                                                      acc[q * 2 + j][nf], 0, 0, 0);
    __builtin_amdgcn_s_setprio(0);
  };

  // prologue: tile0 full + B01,B23,A0A2 of tile1 (A1A3(1) staged at s=0.q0).
  // vmcnt(6) retires all of tile0, leaves tile1's 6 in flight.
  SB(0, 0); SB(0, 64); SB(0, 128); SB(0, 192);
  SA(0, 0); SA(0, 128); SA(0, 64); SA(0, 192);
  SB(1, 0); SB(1, 64); SB(1, 128); SB(1, 192);
  SA(1, 0); SA(1, 128);
  asm volatile("s_waitcnt vmcnt(6)" ::: "memory");
  __builtin_amdgcn_s_barrier();

  for (int s = 0; s < TOT; s++) {
    const int b = s & 1;
    // q0: compute | stage A1A3(s+1) into buf(s^1) (A1A3(s-1) died at (s-1).q3)
    if (s + 1 < TOT) { SA(s + 1, 64); SA(s + 1, 192); }
    PH(b, 0);
    __builtin_amdgcn_s_barrier();
    // q1: compute | stage B01(s+2) into buf(s) (B(s) regs captured at q0)
    if (s + 2 < TOT) { SB(s + 2, 0); SB(s + 2, 64); }
    PH(b, 1);
    __builtin_amdgcn_s_barrier();
    // q2: compute | stage B23(s+2)
    if (s + 2 < TOT) { SB(s + 2, 128); SB(s + 2, 192); }
    PH(b, 2);
    __builtin_amdgcn_s_barrier();
    // q3: compute | stage A0A2(s+2) (A0A2(s) died after q1)
    if (s + 2 < TOT) { SA(s + 2, 0); SA(s + 2, 128); }
    PH(b, 3);
    // single per-step wait: tile s+1 fully resident (retire A1A3(s+1)),
    // tile s+2's 6 loads stay in flight
    if (s + 2 < TOT) asm volatile("s_waitcnt vmcnt(6)" ::: "memory");
    else             asm volatile("s_waitcnt vmcnt(0)" ::: "memory");
    __builtin_amdgcn_s_barrier();
    if ((s & 15) == 15) {  // output-tile boundary: store + zero acc
      long m0c, n0c; tileMN(s >> 4, m0c, n0c);
#pragma unroll
      for (int mf = 0; mf < 8; mf++)
#pragma unroll
        for (int nf = 0; nf < 4; nf++)
#pragma unroll
          for (int r = 0; r < 4; r++) {
            long row = m0c + wm * 128 + mf * 16 + lg * 4 + r;
            long col = n0c + wn * 64 + nf * 16 + l16;
            if (col < N) C[row * (long)N + col] = acc[mf][nf][r];
            acc[mf][nf][r] = 0.f;
          }
    }
  }
}

// ---------------- MFMA flash attention, KVBLK=128, dbuf staging + setprio ----------------
__global__ __launch_bounds__(256) void attn_mfma(const short* __restrict__ qkv,
                                                 const short* __restrict__ vtg,
                                                 short* __restrict__ Oa) {
  int hh = blockIdx.x, qb = blockIdx.y;
  int q0 = qb * 64;
  int tid = threadIdx.x, wv = tid >> 6, lane = tid & 63;
  int l16 = lane & 15, lg = lane >> 4;
  int hcol = hh * 64;
  __shared__ short Ks[2][KVB * 64];
  __shared__ short Vt[2][64 * KVB];
  __shared__ short Pl[4][16 * KVB];

  bf16x8 qf[2];
  {
    const short* qrow = qkv + (long)(q0 + wv * 16 + l16) * QKVD + hcol;
#pragma unroll
    for (int dc = 0; dc < 2; dc++) {
      bf16x8 t = *(const bf16x8*)(qrow + dc * 32 + lg * 8);
#pragma unroll
      for (int j = 0; j < 8; j++) t[j] = f2bf(bf2f(t[j]) * 0.125f);
      qf[dc] = t;
    }
  }
  f32x4 of[4] = {};
  float mrun[4], lrun[4];
#pragma unroll
  for (int r = 0; r < 4; r++) { mrun[r] = -3e38f; lrun[r] = 0.f; }

#define STAGEKV(kt_, b_)                                                        \
  {                                                                             \
    int k0_ = (kt_) * KVB;                                                      \
    _Pragma("unroll")                                                           \
    for (int i = 0; i < 4; i++) {                                               \
      int ca = i * 256 + tid;                                                   \
      int row = ca >> 3, cp = ca & 7, c = cp ^ (row & 7);                       \
      gload_lds16(qkv + (long)(k0_ + row) * QKVD + DIM + hcol + c * 8,          \
                  (short*)Ks[b_] + (i * 256 + wv * 64) * 8);                    \
    }                                                                           \
    _Pragma("unroll")                                                           \
    for (int i = 0; i < 4; i++) {                                               \
      int ca = i * 256 + tid;                                                   \
      int row = ca >> 4, cp = ca & 15, c = cp ^ (row & 7);                      \
      gload_lds16(vtg + (long)(hcol + row) * SEQ + k0_ + c * 8,                 \
                  (short*)Vt[b_] + (i * 256 + wv * 64) * 8);                    \
    }                                                                           \
  }

  int nt = qb / 2 + 1;
  STAGEKV(0, 0);
  asm volatile("s_waitcnt vmcnt(0)" ::: "memory");
  __builtin_amdgcn_s_barrier();

  for (int kt = 0; kt < nt; kt++) {
    const int cur = kt & 1;
    if (kt + 1 < nt) STAGEKV(kt + 1, cur ^ 1);
    int k0 = kt * KVB;

    f32x4 sacc[8] = {};
    __builtin_amdgcn_s_setprio(1);
#pragma unroll
    for (int kc = 0; kc < 8; kc++) {
      int row = kc * 16 + l16;
#pragma unroll
      for (int dc = 0; dc < 2; dc++) {
        bf16x8 kf = *(const bf16x8*)((const char*)Ks[cur] + row * 128 + (((dc * 4 + lg) ^ (row & 7)) * 16));
        sacc[kc] = __builtin_amdgcn_mfma_f32_16x16x32_bf16(qf[dc], kf, sacc[kc], 0, 0, 0);
      }
    }
    __builtin_amdgcn_s_setprio(0);

    float sv[8][4], pf[8][4];
#pragma unroll
    for (int kc = 0; kc < 8; kc++)
#pragma unroll
      for (int r = 0; r < 4; r++) sv[kc][r] = sacc[kc][r];
    if (kt == nt - 1) {
#pragma unroll
      for (int kc = 0; kc < 8; kc++)
#pragma unroll
        for (int r = 0; r < 4; r++) {
          int kg = k0 + kc * 16 + l16;
          int rg = q0 + wv * 16 + lg * 4 + r;
          if (kg > rg) sv[kc][r] = -3e38f;
        }
    }
    float corr[4];
#pragma unroll
    for (int r = 0; r < 4; r++) {
      float m01 = fmaxf(sv[0][r], sv[1][r]), m23 = fmaxf(sv[2][r], sv[3][r]);
      float m45 = fmaxf(sv[4][r], sv[5][r]), m67 = fmaxf(sv[6][r], sv[7][r]);
      float mt = fmaxf(fmaxf(m01, m23), fmaxf(m45, m67));
#pragma unroll
      for (int o = 8; o >= 1; o >>= 1) mt = fmaxf(mt, __shfl_xor(mt, o));
      float mn = fmaxf(mrun[r], mt);
      corr[r] = __expf(mrun[r] - mn);
      mrun[r] = mn;
      float ps = 0.f;
#pragma unroll
      for (int kc = 0; kc < 8; kc++) {
        float p = __expf(sv[kc][r] - mn);
        pf[kc][r] = p;
        ps += p;
      }
#pragma unroll
      for (int o = 8; o >= 1; o >>= 1) ps += __shfl_xor(ps, o);
      lrun[r] = lrun[r] * corr[r] + ps;
    }
#pragma unroll
    for (int c = 0; c < 4; c++)
#pragma unroll
      for (int r = 0; r < 4; r++) of[c][r] *= corr[r];
#pragma unroll
    for (int kc = 0; kc < 8; kc++)
#pragma unroll
      for (int r = 0; r < 4; r++) {
        int row = lg * 4 + r, col = kc * 16 + l16;
        int chunk = col >> 3;
        *(short*)((char*)Pl[wv] + row * 256 + ((chunk ^ (row & 7)) * 16) + (col & 7) * 2) = f2bf(pf[kc][r]);
      }
    bf16x8 pfr[4];
#pragma unroll
    for (int kc2 = 0; kc2 < 4; kc2++) {
      int cl = kc2 * 4 + lg;
      pfr[kc2] = *(const bf16x8*)((const char*)Pl[wv] + l16 * 256 + ((cl ^ (l16 & 7)) * 16));
    }
    __builtin_amdgcn_s_setprio(1);
#pragma unroll
    for (int c = 0; c < 4; c++)
#pragma unroll
      for (int kc2 = 0; kc2 < 4; kc2++) {
        int vrow = c * 16 + l16;
        int cl = kc2 * 4 + lg;
        bf16x8 vf = *(const bf16x8*)((const char*)Vt[cur] + vrow * 256 + ((cl ^ (vrow & 7)) * 16));
        of[c] = __builtin_amdgcn_mfma_f32_16x16x32_bf16(pfr[kc2], vf, of[c], 0, 0, 0);
      }
    __builtin_amdgcn_s_setprio(0);
    if (kt + 1 < nt) {
      asm volatile("s_waitcnt vmcnt(0)" ::: "memory");
      __builtin_amdgcn_s_barrier();
      __builtin_amdgcn_sched_barrier(0);
    }
  }
#undef STAGEKV
#pragma unroll
  for (int c = 0; c < 4; c++)
#pragma unroll
    for (int r = 0; r < 4; r++) {
      int rowg = q0 + wv * 16 + lg * 4 + r;
      int colg = hcol + c * 16 + l16;
      Oa[(long)rowg * DIM + colg] = f2bf(of[c][r] / lrun[r]);
    }
}

// ---------------- orchestration ----------------
extern "C" void kernel_launch(void* const* d_in, const int* in_sizes, int n_in,
                              void* d_out, int out_size, void* d_ws, size_t ws_size,
                              hipStream_t stream) {
  const int* ids = (const int*)d_in[0];
  const float* tok = (const float*)d_in[1];
  const float* pos = (const float*)d_in[2];
  const float* Wq = (const float*)d_in[3];
  const float* bq = (const float*)d_in[4];
  const float* Wk = (const float*)d_in[5];
  const float* bk = (const float*)d_in[6];
  const float* Wv = (const float*)d_in[7];
  const float* bv = (const float*)d_in[8];
  const float* Wo = (const float*)d_in[9];
  const float* bo = (const float*)d_in[10];
  const float* W1 = (const float*)d_in[11];
  const float* b1 = (const float*)d_in[12];
  const float* W2 = (const float*)d_in[13];
  const float* b2 = (const float*)d_in[14];
  const float* ln1w = (const float*)d_in[15];
  const float* ln1b = (const float*)d_in[16];
  const float* ln2w = (const float*)d_in[17];
  const float* ln2b = (const float*)d_in[18];
  const float* lnfw = (const float*)d_in[19];
  const float* lnfb = (const float*)d_in[20];
  const float* lmh = (const float*)d_in[21];
  float* out = (float*)d_out;

  char* wsb = (char*)d_ws;
  float* h = (float*)wsb;                           // 8 MB fp32 residual
  short* x = (short*)(wsb + 8388608);               // 4 MB bf16 LN out
  char* big = wsb + 8388608 + 4194304;
  short* qkv  = (short*)big;                        // 12 MB   [S][3072]
  short* a    = (short*)(big + 12582912);           // 4 MB    [S][1024]
  short* vt   = (short*)(big + 16777216);           // 4 MB    [1024][S]
  short* fbuf = (short*)(big + 20971520);           // 16 MB   [S][4096]
  float* pproj = (float*)fbuf;                      // proj partials: 2x8MB
  float* pffn2 = (float*)big;                       // ffn2 partials: 2x8MB (qkv+a free)
  char* wdyn = big + 37748736;
  short* wqkvT = (short*)wdyn;                      // 6 MB  [3072][1024]
  short* woT   = (short*)(wdyn + 6291456);          // 2 MB  [1024][1024]
  short* w1T   = (short*)(wdyn + 8388608);          // 8 MB  [4096][1024]
  short* w2T   = (short*)(wdyn + 16777216);         // 8 MB  [1024][4096]
  float* bias3 = (float*)(wdyn + 25165824);         // 12 KB
  short* lmhB = (short*)big;                        // 103 MB, reused after layers

  embed_kernel<<<(SEQ * DIM + 255) / 256, 256, 0, stream>>>(ids, tok, pos, h);
  ln_kernel<<<SEQ, 256, 0, stream>>>(h, ln1w, ln1b, x);  // layer 0 ln1

  dim3 gQKV(SEQ / 64, QKVD / 128);                  // 32 x 24 = 768
  dim3 gPROJ(SEQ / 64, DIM / 128, 2);               // 32 x 8 x 2 = 512
  dim3 gFFN1(SEQ / 128, FFN / 128);                 // 16 x 32 = 512
  dim3 gFFN2(SEQ / 64, DIM / 128, 2);               // 32 x 8 x 2 = 512

  for (int l = 0; l < NLAYER; l++) {
    Prep p;
    p.wq = Wq + (long)l * DIM * DIM; p.wk = Wk + (long)l * DIM * DIM;
    p.wv = Wv + (long)l * DIM * DIM; p.wo = Wo + (long)l * DIM * DIM;
    p.w1 = W1 + (long)l * DIM * FFN; p.w2 = W2 + (long)l * FFN * DIM;
    p.bq = bq + (long)l * DIM; p.bk = bk + (long)l * DIM; p.bv = bv + (long)l * DIM;
    p.qkvT = wqkvT; p.woT = woT; p.w1T = w1T; p.w2T = w2T; p.bias3 = bias3;
    prep_kernel<<<3073, 256, 0, stream>>>(p);

    gemm_small<false, true, true, 1, true><<<gQKV, 256, 0, stream>>>(x, wqkvT, bias3, qkv, QKVD, DIM);
    transpose_v<<<dim3(SEQ / 64, DIM / 64), 256, 0, stream>>>(qkv, vt);
    attn_mfma<<<dim3(NHEAD, SEQ / 64), 256, 0, stream>>>(qkv, vt, a);
    gemm_small<false, false, false, 2, true><<<gPROJ, 256, 0, stream>>>(a, woT, nullptr, pproj, DIM, DIM);
    reduce_ln<<<SEQ, 256, 0, stream>>>(pproj, bo + (long)l * DIM,
                                       ln2w + (long)l * DIM, ln2b + (long)l * DIM, h, x);
    gemm4<true, true, true, true><<<gFFN1, 256, 0, stream>>>(x, w1T, b1 + (long)l * FFN, fbuf, FFN, DIM);
    gemm_small<false, false, false, 2, true><<<gFFN2, 256, 0, stream>>>(fbuf, w2T, nullptr, pffn2, DIM, FFN);
    const float* nw = (l < NLAYER - 1) ? ln1w + (long)(l + 1) * DIM : lnfw;
    const float* nb = (l < NLAYER - 1) ? ln1b + (long)(l + 1) * DIM : lnfb;
    reduce_ln<<<SEQ, 256, 0, stream>>>(pffn2, b2 + (long)l * DIM, nw, nb, h, x);
  }

  conv_bf16<<<2048, 256, 0, stream>>>(lmh, lmhB, (long)VOCAB * DIM / 4);
  gemm256p<<<dim3(256), 512, 0, stream>>>(x, lmhB, out, VOCAB, DIM,
                                          (SEQ / 256) * ((VOCAB + 255) / 256));
}

// Round 12
// 1109.899 us; speedup vs baseline: 1.0376x; 1.0051x over previous
//
#include <hip/hip_runtime.h>
#include <math.h>
#include <stdint.h>

// GPT fwd, L=4 D=1024 H=16 HS=64 F=4096 V=50257 S=2048.
// Round 12: gemm256b for lm_head — 256x128 tile, BK=32, 8 waves (4Mx2N,
// per-wave 64x64 -> acc 64 VGPR), 3x24KB LDS => 2 blocks/CU (16 waves),
// gemm4-proven pipeline skeleton (distance-2, counted vmcnt(3)), XCD
// bijective remap. Everything else identical to R11 (1115 us).

#define SEQ 2048
#define DIM 1024
#define NHEAD 16
#define FFN 4096
#define VOCAB 50257
#define NLAYER 4
#define LNEPS 1e-5f
#define QKVD 3072
#define KVB 128

using bf16x8 = __attribute__((ext_vector_type(8))) short;
using s16x4  = __attribute__((ext_vector_type(4))) short;
using f32x4  = __attribute__((ext_vector_type(4))) float;
using fl4    = __attribute__((ext_vector_type(4))) float;

static __device__ __forceinline__ short f2bf(float f) {
  uint32_t u = __float_as_uint(f);
  u = (u + 0x7fffu + ((u >> 16) & 1u)) >> 16;
  return (short)u;
}
static __device__ __forceinline__ float bf2f(short s) {
  return __uint_as_float(((uint32_t)(uint16_t)s) << 16);
}
static __device__ __forceinline__ void gload_lds16(const void* g, void* l) {
  __builtin_amdgcn_global_load_lds((const __attribute__((address_space(1))) void*)g,
                                   (__attribute__((address_space(3))) void*)l, 16, 0, 0);
}

// ---------------- embedding (fp32 h) ----------------
__global__ void embed_kernel(const int* __restrict__ ids,
                             const float* __restrict__ tok,
                             const float* __restrict__ pos,
                             float* __restrict__ h) {
  int i = blockIdx.x * blockDim.x + threadIdx.x;
  if (i < SEQ * DIM) {
    int s = i / DIM, d = i % DIM;
    h[i] = tok[(long)ids[s] * DIM + d] + pos[i];
  }
}

// ---------------- layernorm: fp32 in -> bf16 out (layer0 ln1 only) ----------------
__global__ void ln_kernel(const float* __restrict__ x, const float* __restrict__ w,
                          const float* __restrict__ b, short* __restrict__ y) {
  int row = blockIdx.x;
  const float* xr = x + (long)row * DIM;
  short* yr = y + (long)row * DIM;
  int tid = threadIdx.x;
  float v0 = xr[tid], v1 = xr[tid + 256], v2 = xr[tid + 512], v3 = xr[tid + 768];
  __shared__ float red[8];
  float s = v0 + v1 + v2 + v3;
#pragma unroll
  for (int o = 32; o >= 1; o >>= 1) s += __shfl_xor(s, o);
  if ((tid & 63) == 0) red[tid >> 6] = s;
  __syncthreads();
  float mean = (red[0] + red[1] + red[2] + red[3]) * (1.f / DIM);
  float d0 = v0 - mean, d1 = v1 - mean, d2 = v2 - mean, d3 = v3 - mean;
  float q = d0 * d0 + d1 * d1 + d2 * d2 + d3 * d3;
#pragma unroll
  for (int o = 32; o >= 1; o >>= 1) q += __shfl_xor(q, o);
  if ((tid & 63) == 0) red[4 + (tid >> 6)] = q;
  __syncthreads();
  float var = (red[4] + red[5] + red[6] + red[7]) * (1.f / DIM);
  float rstd = rsqrtf(var + LNEPS);
  yr[tid]       = f2bf(d0 * rstd * w[tid] + b[tid]);
  yr[tid + 256] = f2bf(d1 * rstd * w[tid + 256] + b[tid + 256]);
  yr[tid + 512] = f2bf(d2 * rstd * w[tid + 512] + b[tid + 512]);
  yr[tid + 768] = f2bf(d3 * rstd * w[tid + 768] + b[tid + 768]);
}

// ---------------- fused: h += bias + part0 + part1; x = LN(h) bf16 ----------------
__global__ void reduce_ln(const float* __restrict__ part, const float* __restrict__ bias,
                          const float* __restrict__ lnw, const float* __restrict__ lnb,
                          float* __restrict__ h, short* __restrict__ x) {
  const long MN = (long)SEQ * DIM;
  int row = blockIdx.x, tid = threadIdx.x;
  long off = (long)row * DIM + tid * 4;
  fl4 hv = *(const fl4*)(h + off);
  fl4 p0 = *(const fl4*)(part + off);
  fl4 p1 = *(const fl4*)(part + MN + off);
  fl4 bv = *(const fl4*)(bias + tid * 4);
  float v[4];
#pragma unroll
  for (int u = 0; u < 4; u++) v[u] = hv[u] + p0[u] + p1[u] + bv[u];
  __shared__ float red[8];
  float s = v[0] + v[1] + v[2] + v[3];
#pragma unroll
  for (int o = 32; o >= 1; o >>= 1) s += __shfl_xor(s, o);
  if ((tid & 63) == 0) red[tid >> 6] = s;
  __syncthreads();
  float mean = (red[0] + red[1] + red[2] + red[3]) * (1.f / DIM);
  float d[4], q = 0.f;
#pragma unroll
  for (int u = 0; u < 4; u++) { d[u] = v[u] - mean; q += d[u] * d[u]; }
#pragma unroll
  for (int o = 32; o >= 1; o >>= 1) q += __shfl_xor(q, o);
  if ((tid & 63) == 0) red[4 + (tid >> 6)] = q;
  fl4 hw; hw[0] = v[0]; hw[1] = v[1]; hw[2] = v[2]; hw[3] = v[3];
  *(fl4*)(h + off) = hw;
  __syncthreads();
  float var = (red[4] + red[5] + red[6] + red[7]) * (1.f / DIM);
  float rstd = rsqrtf(var + LNEPS);
  fl4 w = *(const fl4*)(lnw + tid * 4);
  fl4 bb = *(const fl4*)(lnb + tid * 4);
  s16x4 o;
#pragma unroll
  for (int u = 0; u < 4; u++) o[u] = f2bf(d[u] * rstd * w[u] + bb[u]);
  *(s16x4*)(x + off) = o;
}

// ---------------- merged per-layer weight prep: 6 transposes + bias concat ----------------
struct Prep {
  const float *wq, *wk, *wv, *wo, *w1, *w2, *bq, *bk, *bv;
  short *qkvT, *woT, *w1T, *w2T;
  float* bias3;
};
__global__ void prep_kernel(Prep p) {
  int t = blockIdx.x;
  if (t >= 3072) {
    for (int k = threadIdx.x; k < QKVD; k += 256)
      p.bias3[k] = k < DIM ? p.bq[k] : (k < 2 * DIM ? p.bk[k - DIM] : p.bv[k - 2 * DIM]);
    return;
  }
  const float* in; short* out; int Kd, Nd, r0, c0;
  if (t < 1024) {
    int m = t >> 8, lt = t & 255;
    const float* srcs[4] = {p.wq, p.wk, p.wv, p.wo};
    short* dsts[4] = {p.qkvT, p.qkvT + (long)DIM * DIM, p.qkvT + (long)2 * DIM * DIM, p.woT};
    in = srcs[m]; out = dsts[m]; Kd = DIM; Nd = DIM;
    c0 = (lt & 15) * 64; r0 = (lt >> 4) * 64;
  } else if (t < 2048) {
    int lt = t - 1024; in = p.w1; out = p.w1T; Kd = DIM; Nd = FFN;
    c0 = (lt & 63) * 64; r0 = (lt >> 6) * 64;
  } else {
    int lt = t - 2048; in = p.w2; out = p.w2T; Kd = FFN; Nd = DIM;
    c0 = (lt & 15) * 64; r0 = (lt >> 4) * 64;
  }
  __shared__ float ts[64][65];
  int tid = threadIdx.x;
  int lr = tid >> 4, lc4 = (tid & 15) * 4;
#pragma unroll
  for (int i = 0; i < 4; i++) {
    fl4 v = *(const fl4*)(in + (long)(r0 + lr + i * 16) * Nd + c0 + lc4);
    ts[lr + i * 16][lc4] = v[0]; ts[lr + i * 16][lc4 + 1] = v[1];
    ts[lr + i * 16][lc4 + 2] = v[2]; ts[lr + i * 16][lc4 + 3] = v[3];
  }
  __syncthreads();
#pragma unroll
  for (int i = 0; i < 2; i++) {
    int oc = (tid >> 3) + i * 32, seg = tid & 7;
    bf16x8 o;
#pragma unroll
    for (int u = 0; u < 8; u++) o[u] = f2bf(ts[seg * 8 + u][oc]);
    *(bf16x8*)(out + (long)(c0 + oc) * Kd + r0 + seg * 8) = o;
  }
}

// ---------------- V transpose: qkv[s][2D+c] -> vt[c][s] ----------------
__global__ void transpose_v(const short* __restrict__ qkv, short* __restrict__ vt) {
  __shared__ short t[64][72];
  int s0 = blockIdx.x * 64, c0 = blockIdx.y * 64;
  int tid = threadIdx.x;
#pragma unroll
  for (int i = 0; i < 2; i++) {
    int ca = i * 256 + tid;
    int row = ca >> 3, cp = ca & 7;
    bf16x8 v = *(const bf16x8*)(qkv + (long)(s0 + row) * QKVD + 2 * DIM + c0 + cp * 8);
    *(bf16x8*)&t[row][cp * 8] = v;
  }
  __syncthreads();
#pragma unroll
  for (int i = 0; i < 2; i++) {
    int ca = i * 256 + tid;
    int crow = ca >> 3, sp = ca & 7;
    bf16x8 o;
#pragma unroll
    for (int u = 0; u < 8; u++) o[u] = t[sp * 8 + u][crow];
    *(bf16x8*)(vt + (long)(c0 + crow) * SEQ + s0 + sp * 8) = o;
  }
}

// ---------------- fp32 -> bf16 convert (lm_head) ----------------
__global__ void conv_bf16(const float* __restrict__ in, short* __restrict__ out, long n4) {
  long i = (long)blockIdx.x * blockDim.x + threadIdx.x;
  long stride = (long)gridDim.x * blockDim.x;
  for (; i < n4; i += stride) {
    fl4 v = *(const fl4*)(in + i * 4);
    s16x4 o;
    o[0] = f2bf(v[0]); o[1] = f2bf(v[1]); o[2] = f2bf(v[2]); o[3] = f2bf(v[3]);
    *(s16x4*)(out + i * 4) = o;
  }
}

// ---------------- gemm_small: 64x128 tile, BK=32, 4 waves (QKV/proj/FFN2) ----------------
template <bool GELU, bool BIAS, bool OUTBF16, int KS, bool XCDSWZ>
__global__ __launch_bounds__(256, 4) void gemm_small(
    const short* __restrict__ A, const short* __restrict__ Bt,
    const float* __restrict__ bias, void* __restrict__ Cout, int N, int Kfull) {
  __shared__ short lds[3][(64 + 128) * 32];  // 3 x 12KB
  const int tid = threadIdx.x, wid = tid >> 6, lane = tid & 63;
  const int l16 = lane & 15, lg = lane >> 4;
  int bx = blockIdx.x, by = blockIdx.y;
  if (XCDSWZ) {
    int gx = gridDim.x, nwg = gx * gridDim.y;
    int flat = by * gx + bx;
    int nf = (flat & 7) * (nwg >> 3) + (flat >> 3);
    bx = nf % gx; by = nf / gx;
  }
  const long m0 = (long)bx * 64, n0 = (long)by * 128;
  const int K = Kfull / KS;
  const int kbase = blockIdx.z * K;
  const int NT = K / 32;
  const int wm = wid >> 1, wn = wid & 1;

#define STG(t, b)                                                               \
  {                                                                             \
    short* As_ = lds[b];                                                        \
    short* Bs_ = lds[b] + 64 * 32;                                              \
    int kk_ = kbase + (t) * 32;                                                 \
    {                                                                           \
      int row_ = tid >> 2, cp_ = tid & 3, c_ = cp_ ^ ((row_ >> 1) & 3);         \
      gload_lds16(A + (m0 + row_) * (long)Kfull + kk_ + c_ * 8,                 \
                  As_ + (wid * 64) * 8);                                        \
    }                                                                           \
    _Pragma("unroll")                                                           \
    for (int i_ = 0; i_ < 2; i_++) {                                            \
      int ca_ = i_ * 256 + tid;                                                 \
      int row_ = ca_ >> 2, cp_ = ca_ & 3, c_ = cp_ ^ ((row_ >> 1) & 3);         \
      gload_lds16(Bt + (long)(n0 + row_) * Kfull + kk_ + c_ * 8,                \
                  Bs_ + (i_ * 256 + wid * 64) * 8);                             \
    }                                                                           \
  }

  f32x4 acc[2][4] = {};
  STG(0, 0);
  STG(1, 1);
  asm volatile("s_waitcnt vmcnt(3)" ::: "memory");
  __builtin_amdgcn_s_barrier();
  __builtin_amdgcn_sched_barrier(0);

  for (int t = 0; t < NT; t++) {
    const int b = t % 3;
    if (t + 2 < NT) STG(t + 2, (t + 2) % 3);
    const short* As = lds[b];
    const short* Bs = lds[b] + 64 * 32;
    bf16x8 af[2], bfr[4];
#pragma unroll
    for (int m = 0; m < 2; m++) {
      int row = wm * 32 + m * 16 + l16;
      af[m] = *(const bf16x8*)((const char*)As + row * 64 + ((lg ^ ((row >> 1) & 3)) * 16));
    }
#pragma unroll
    for (int n = 0; n < 4; n++) {
      int row = wn * 64 + n * 16 + l16;
      bfr[n] = *(const bf16x8*)((const char*)Bs + row * 64 + ((lg ^ ((row >> 1) & 3)) * 16));
    }
    __builtin_amdgcn_s_setprio(1);
#pragma unroll
    for (int m = 0; m < 2; m++)
#pragma unroll
      for (int n = 0; n < 4; n++)
        acc[m][n] = __builtin_amdgcn_mfma_f32_16x16x32_bf16(af[m], bfr[n], acc[m][n], 0, 0, 0);
    __builtin_amdgcn_s_setprio(0);
    if (t + 2 < NT) {
      asm volatile("s_waitcnt vmcnt(3)" ::: "memory");
    } else if (t + 1 < NT) {
      asm volatile("s_waitcnt vmcnt(0)" ::: "memory");
    }
    if (t + 1 < NT) {
      __builtin_amdgcn_s_barrier();
      __builtin_amdgcn_sched_barrier(0);
    }
  }
#undef STG

  const int lr4 = lg * 4;
  if (KS == 1) {
#pragma unroll
    for (int m = 0; m < 2; m++)
#pragma unroll
      for (int n = 0; n < 4; n++)
#pragma unroll
        for (int r = 0; r < 4; r++) {
          long row = m0 + wm * 32 + m * 16 + lr4 + r;
          long col = n0 + wn * 64 + n * 16 + l16;
          float v = acc[m][n][r];
          if (BIAS) v += bias[col];
          if (GELU) v = 0.5f * v * (1.f + erff(v * 0.70710678118f));
          if (OUTBF16) ((short*)Cout)[row * (long)N + col] = f2bf(v);
          else ((float*)Cout)[row * (long)N + col] = v;
        }
  } else {
    long M = (long)gridDim.x * 64;
    float* P = (float*)Cout + (long)blockIdx.z * M * N;
#pragma unroll
    for (int m = 0; m < 2; m++)
#pragma unroll
      for (int n = 0; n < 4; n++)
#pragma unroll
        for (int r = 0; r < 4; r++) {
          long row = m0 + wm * 32 + m * 16 + lr4 + r;
          long col = n0 + wn * 64 + n * 16 + l16;
          P[row * (long)N + col] = acc[m][n][r];
        }
  }
}

// ---------------- gemm4: 128x128, BK=32, 3 blocks/CU (FFN1) ----------------
template <bool GELU, bool BIAS, bool OUTBF16, bool XCDSWZ>
__global__ __launch_bounds__(256, 3) void gemm4(
    const short* __restrict__ A, const short* __restrict__ Bt,
    const float* __restrict__ bias, void* __restrict__ Cout, int N, int Kfull) {
  __shared__ short lds[3][(128 + 128) * 32];  // 3 x 16KB
  const int tid = threadIdx.x, wid = tid >> 6, lane = tid & 63;
  const int l16 = lane & 15, lg = lane >> 4;
  int bx = blockIdx.x, by = blockIdx.y;
  if (XCDSWZ) {
    int gx = gridDim.x, nwg = gx * gridDim.y;
    int flat = by * gx + bx;
    int nf = (flat & 7) * (nwg >> 3) + (flat >> 3);
    bx = nf % gx; by = nf / gx;
  }
  const long m0 = (long)bx * 128, n0 = (long)by * 128;
  const int NT = Kfull / 32;
  const int wr = (wid >> 1) * 64, wc = (wid & 1) * 64;

#define STAGE4(t, b)                                                            \
  {                                                                             \
    short* As_ = lds[b];                                                        \
    short* Bs_ = lds[b] + 128 * 32;                                             \
    int kk_ = (t) * 32;                                                         \
    _Pragma("unroll")                                                           \
    for (int i_ = 0; i_ < 2; i_++) {                                            \
      int ca_ = i_ * 256 + tid;                                                 \
      int row_ = ca_ >> 2, cp_ = ca_ & 3, c_ = cp_ ^ ((row_ >> 1) & 3);         \
      gload_lds16(A + (m0 + row_) * (long)Kfull + kk_ + c_ * 8,                 \
                  As_ + (i_ * 256 + wid * 64) * 8);                             \
    }                                                                           \
    _Pragma("unroll")                                                           \
    for (int i_ = 0; i_ < 2; i_++) {                                            \
      int ca_ = i_ * 256 + tid;                                                 \
      int row_ = ca_ >> 2, cp_ = ca_ & 3, c_ = cp_ ^ ((row_ >> 1) & 3);         \
      gload_lds16(Bt + (long)(n0 + row_) * Kfull + kk_ + c_ * 8,                \
                  Bs_ + (i_ * 256 + wid * 64) * 8);                             \
    }                                                                           \
  }

  f32x4 acc[4][4] = {};
  STAGE4(0, 0);
  STAGE4(1, 1);
  asm volatile("s_waitcnt vmcnt(4)" ::: "memory");
  __builtin_amdgcn_s_barrier();
  __builtin_amdgcn_sched_barrier(0);

  for (int t = 0; t < NT; t++) {
    const int b = t % 3;
    if (t + 2 < NT) STAGE4(t + 2, (t + 2) % 3);
    const short* As = lds[b];
    const short* Bs = lds[b] + 128 * 32;
    bf16x8 af[4], bfr[4];
#pragma unroll
    for (int m = 0; m < 4; m++) {
      int row = wr + m * 16 + l16;
      af[m] = *(const bf16x8*)((const char*)As + row * 64 + ((lg ^ ((row >> 1) & 3)) * 16));
    }
#pragma unroll
    for (int n = 0; n < 4; n++) {
      int row = wc + n * 16 + l16;
      bfr[n] = *(const bf16x8*)((const char*)Bs + row * 64 + ((lg ^ ((row >> 1) & 3)) * 16));
    }
    __builtin_amdgcn_s_setprio(1);
#pragma unroll
    for (int m = 0; m < 4; m++)
#pragma unroll
      for (int n = 0; n < 4; n++)
        acc[m][n] = __builtin_amdgcn_mfma_f32_16x16x32_bf16(af[m], bfr[n], acc[m][n], 0, 0, 0);
    __builtin_amdgcn_s_setprio(0);
    if (t + 2 < NT) {
      asm volatile("s_waitcnt vmcnt(4)" ::: "memory");
    } else if (t + 1 < NT) {
      asm volatile("s_waitcnt vmcnt(0)" ::: "memory");
    }
    if (t + 1 < NT) {
      __builtin_amdgcn_s_barrier();
      __builtin_amdgcn_sched_barrier(0);
    }
  }
#undef STAGE4

  const int lr4 = lg * 4;
#pragma unroll
  for (int m = 0; m < 4; m++)
#pragma unroll
    for (int n = 0; n < 4; n++)
#pragma unroll
      for (int r = 0; r < 4; r++) {
        long row = m0 + wr + m * 16 + lr4 + r;
        long col = n0 + wc + n * 16 + l16;
        float v = acc[m][n][r];
        if (BIAS) v += bias[col];
        if (GELU) v = 0.5f * v * (1.f + erff(v * 0.70710678118f));
        if (OUTBF16) ((short*)Cout)[row * (long)N + col] = f2bf(v);
        else ((float*)Cout)[row * (long)N + col] = v;
      }
}

// ---------------- gemm256b: lm_head GEMM, 2 blocks/CU ----------------
// 256x128 tile, BK=32, 8 waves (4M x 2N, per-wave 64x64 -> acc 64 VGPR),
// 3 x 24KB LDS (72KB -> 2 blocks/CU = 16 waves/CU). gemm4-proven pipeline:
// distance-2 prefetch, counted vmcnt(3) (3 gloads/stage: A 2, B 1), 2-row
// chunk-XOR swizzle. Grid 8(m,fast) x 393(n) + XCD bijective remap: the 8
// consecutive same-XCD blocks share one 128-row B panel (L2-resident).
__global__ __launch_bounds__(512, 4) void gemm256b(
    const short* __restrict__ A, const short* __restrict__ Bt,
    float* __restrict__ C, int N, int K) {
  __shared__ short lds[3][(256 + 128) * 32];  // 3 x 24KB
  const int tid = threadIdx.x, wid = tid >> 6, lane = tid & 63;
  const int l16 = lane & 15, lg = lane >> 4;
  int bx = blockIdx.x, by = blockIdx.y;
  {  // XCD bijective remap; nwg = 8*393 = 3144 (%8 == 0)
    int gx = gridDim.x, nwg = gx * gridDim.y;
    int flat = by * gx + bx;
    int nf = (flat & 7) * (nwg >> 3) + (flat >> 3);
    bx = nf % gx; by = nf / gx;
  }
  const long m0 = (long)bx * 256, n0 = (long)by * 128;
  const int NT = K / 32;
  const int wm = wid >> 1, wn = wid & 1;

#define STG6(t, b)                                                              \
  {                                                                             \
    short* As_ = lds[b];                                                        \
    short* Bs_ = lds[b] + 256 * 32;                                             \
    int kk_ = (t) * 32;                                                         \
    _Pragma("unroll")                                                           \
    for (int i_ = 0; i_ < 2; i_++) {                                            \
      int ca_ = i_ * 512 + tid;                                                 \
      int row_ = ca_ >> 2, cp_ = ca_ & 3, c_ = cp_ ^ ((row_ >> 1) & 3);         \
      gload_lds16(A + (m0 + row_) * (long)K + kk_ + c_ * 8,                     \
                  As_ + (i_ * 512 + wid * 64) * 8);                             \
    }                                                                           \
    {                                                                           \
      int row_ = tid >> 2, cp_ = tid & 3, c_ = cp_ ^ ((row_ >> 1) & 3);         \
      int rowb_ = (int)n0 + row_;                                               \
      if (rowb_ > N - 1) rowb_ = N - 1;                                         \
      gload_lds16(Bt + (long)rowb_ * K + kk_ + c_ * 8,                          \
                  Bs_ + (wid * 64) * 8);                                        \
    }                                                                           \
  }

  f32x4 acc[4][4] = {};
  STG6(0, 0);
  STG6(1, 1);
  asm volatile("s_waitcnt vmcnt(3)" ::: "memory");
  __builtin_amdgcn_s_barrier();
  __builtin_amdgcn_sched_barrier(0);

  for (int t = 0; t < NT; t++) {
    const int b = t % 3;
    if (t + 2 < NT) STG6(t + 2, (t + 2) % 3);
    const short* As = lds[b];
    const short* Bs = lds[b] + 256 * 32;
    bf16x8 bfr[4];
#pragma unroll
    for (int n = 0; n < 4; n++) {
      int row = wn * 64 + n * 16 + l16;
      bfr[n] = *(const bf16x8*)((const char*)Bs + row * 64 + ((lg ^ ((row >> 1) & 3)) * 16));
    }
    __builtin_amdgcn_s_setprio(1);
#pragma unroll
    for (int m = 0; m < 4; m++) {
      int row = wm * 64 + m * 16 + l16;
      bf16x8 af = *(const bf16x8*)((const char*)As + row * 64 + ((lg ^ ((row >> 1) & 3)) * 16));
#pragma unroll
      for (int n = 0; n < 4; n++)
        acc[m][n] = __builtin_amdgcn_mfma_f32_16x16x32_bf16(af, bfr[n], acc[m][n], 0, 0, 0);
    }
    __builtin_amdgcn_s_setprio(0);
    if (t + 2 < NT) {
      asm volatile("s_waitcnt vmcnt(3)" ::: "memory");
    } else if (t + 1 < NT) {
      asm volatile("s_waitcnt vmcnt(0)" ::: "memory");
    }
    if (t + 1 < NT) {
      __builtin_amdgcn_s_barrier();
      __builtin_amdgcn_sched_barrier(0);
    }
  }
#undef STG6

  const int lr4 = lg * 4;
#pragma unroll
  for (int m = 0; m < 4; m++)
#pragma unroll
    for (int n = 0; n < 4; n++)
#pragma unroll
      for (int r = 0; r < 4; r++) {
        long row = m0 + wm * 64 + m * 16 + lr4 + r;
        long col = n0 + wn * 64 + n * 16 + l16;
        if (col < N) C[row * (long)N + col] = acc[m][n][r];
      }
}

// ---------------- MFMA flash attention, KVBLK=128, dbuf staging + setprio ----------------
__global__ __launch_bounds__(256) void attn_mfma(const short* __restrict__ qkv,
                                                 const short* __restrict__ vtg,
                                                 short* __restrict__ Oa) {
  int hh = blockIdx.x, qb = blockIdx.y;
  int q0 = qb * 64;
  int tid = threadIdx.x, wv = tid >> 6, lane = tid & 63;
  int l16 = lane & 15, lg = lane >> 4;
  int hcol = hh * 64;
  __shared__ short Ks[2][KVB * 64];
  __shared__ short Vt[2][64 * KVB];
  __shared__ short Pl[4][16 * KVB];

  bf16x8 qf[2];
  {
    const short* qrow = qkv + (long)(q0 + wv * 16 + l16) * QKVD + hcol;
#pragma unroll
    for (int dc = 0; dc < 2; dc++) {
      bf16x8 t = *(const bf16x8*)(qrow + dc * 32 + lg * 8);
#pragma unroll
      for (int j = 0; j < 8; j++) t[j] = f2bf(bf2f(t[j]) * 0.125f);
      qf[dc] = t;
    }
  }
  f32x4 of[4] = {};
  float mrun[4], lrun[4];
#pragma unroll
  for (int r = 0; r < 4; r++) { mrun[r] = -3e38f; lrun[r] = 0.f; }

#define STAGEKV(kt_, b_)                                                        \
  {                                                                             \
    int k0_ = (kt_) * KVB;                                                      \
    _Pragma("unroll")                                                           \
    for (int i = 0; i < 4; i++) {                                               \
      int ca = i * 256 + tid;                                                   \
      int row = ca >> 3, cp = ca & 7, c = cp ^ (row & 7);                       \
      gload_lds16(qkv + (long)(k0_ + row) * QKVD + DIM + hcol + c * 8,          \
                  (short*)Ks[b_] + (i * 256 + wv * 64) * 8);                    \
    }                                                                           \
    _Pragma("unroll")                                                           \
    for (int i = 0; i < 4; i++) {                                               \
      int ca = i * 256 + tid;                                                   \
      int row = ca >> 4, cp = ca & 15, c = cp ^ (row & 7);                      \
      gload_lds16(vtg + (long)(hcol + row) * SEQ + k0_ + c * 8,                 \
                  (short*)Vt[b_] + (i * 256 + wv * 64) * 8);                    \
    }                                                                           \
  }

  int nt = qb / 2 + 1;
  STAGEKV(0, 0);
  asm volatile("s_waitcnt vmcnt(0)" ::: "memory");
  __builtin_amdgcn_s_barrier();

  for (int kt = 0; kt < nt; kt++) {
    const int cur = kt & 1;
    if (kt + 1 < nt) STAGEKV(kt + 1, cur ^ 1);
    int k0 = kt * KVB;

    f32x4 sacc[8] = {};
    __builtin_amdgcn_s_setprio(1);
#pragma unroll
    for (int kc = 0; kc < 8; kc++) {
      int row = kc * 16 + l16;
#pragma unroll
      for (int dc = 0; dc < 2; dc++) {
        bf16x8 kf = *(const bf16x8*)((const char*)Ks[cur] + row * 128 + (((dc * 4 + lg) ^ (row & 7)) * 16));
        sacc[kc] = __builtin_amdgcn_mfma_f32_16x16x32_bf16(qf[dc], kf, sacc[kc], 0, 0, 0);
      }
    }
    __builtin_amdgcn_s_setprio(0);

    float sv[8][4], pf[8][4];
#pragma unroll
    for (int kc = 0; kc < 8; kc++)
#pragma unroll
      for (int r = 0; r < 4; r++) sv[kc][r] = sacc[kc][r];
    if (kt == nt - 1) {
#pragma unroll
      for (int kc = 0; kc < 8; kc++)
#pragma unroll
        for (int r = 0; r < 4; r++) {
          int kg = k0 + kc * 16 + l16;
          int rg = q0 + wv * 16 + lg * 4 + r;
          if (kg > rg) sv[kc][r] = -3e38f;
        }
    }
    float corr[4];
#pragma unroll
    for (int r = 0; r < 4; r++) {
      float m01 = fmaxf(sv[0][r], sv[1][r]), m23 = fmaxf(sv[2][r], sv[3][r]);
      float m45 = fmaxf(sv[4][r], sv[5][r]), m67 = fmaxf(sv[6][r], sv[7][r]);
      float mt = fmaxf(fmaxf(m01, m23), fmaxf(m45, m67));
#pragma unroll
      for (int o = 8; o >= 1; o >>= 1) mt = fmaxf(mt, __shfl_xor(mt, o));
      float mn = fmaxf(mrun[r], mt);
      corr[r] = __expf(mrun[r] - mn);
      mrun[r] = mn;
      float ps = 0.f;
#pragma unroll
      for (int kc = 0; kc < 8; kc++) {
        float p = __expf(sv[kc][r] - mn);
        pf[kc][r] = p;
        ps += p;
      }
#pragma unroll
      for (int o = 8; o >= 1; o >>= 1) ps += __shfl_xor(ps, o);
      lrun[r] = lrun[r] * corr[r] + ps;
    }
#pragma unroll
    for (int c = 0; c < 4; c++)
#pragma unroll
      for (int r = 0; r < 4; r++) of[c][r] *= corr[r];
#pragma unroll
    for (int kc = 0; kc < 8; kc++)
#pragma unroll
      for (int r = 0; r < 4; r++) {
        int row = lg * 4 + r, col = kc * 16 + l16;
        int chunk = col >> 3;
        *(short*)((char*)Pl[wv] + row * 256 + ((chunk ^ (row & 7)) * 16) + (col & 7) * 2) = f2bf(pf[kc][r]);
      }
    bf16x8 pfr[4];
#pragma unroll
    for (int kc2 = 0; kc2 < 4; kc2++) {
      int cl = kc2 * 4 + lg;
      pfr[kc2] = *(const bf16x8*)((const char*)Pl[wv] + l16 * 256 + ((cl ^ (l16 & 7)) * 16));
    }
    __builtin_amdgcn_s_setprio(1);
#pragma unroll
    for (int c = 0; c < 4; c++)
#pragma unroll
      for (int kc2 = 0; kc2 < 4; kc2++) {
        int vrow = c * 16 + l16;
        int cl = kc2 * 4 + lg;
        bf16x8 vf = *(const bf16x8*)((const char*)Vt[cur] + vrow * 256 + ((cl ^ (vrow & 7)) * 16));
        of[c] = __builtin_amdgcn_mfma_f32_16x16x32_bf16(pfr[kc2], vf, of[c], 0, 0, 0);
      }
    __builtin_amdgcn_s_setprio(0);
    if (kt + 1 < nt) {
      asm volatile("s_waitcnt vmcnt(0)" ::: "memory");
      __builtin_amdgcn_s_barrier();
      __builtin_amdgcn_sched_barrier(0);
    }
  }
#undef STAGEKV
#pragma unroll
  for (int c = 0; c < 4; c++)
#pragma unroll
    for (int r = 0; r < 4; r++) {
      int rowg = q0 + wv * 16 + lg * 4 + r;
      int colg = hcol + c * 16 + l16;
      Oa[(long)rowg * DIM + colg] = f2bf(of[c][r] / lrun[r]);
    }
}

// ---------------- orchestration ----------------
extern "C" void kernel_launch(void* const* d_in, const int* in_sizes, int n_in,
                              void* d_out, int out_size, void* d_ws, size_t ws_size,
                              hipStream_t stream) {
  const int* ids = (const int*)d_in[0];
  const float* tok = (const float*)d_in[1];
  const float* pos = (const float*)d_in[2];
  const float* Wq = (const float*)d_in[3];
  const float* bq = (const float*)d_in[4];
  const float* Wk = (const float*)d_in[5];
  const float* bk = (const float*)d_in[6];
  const float* Wv = (const float*)d_in[7];
  const float* bv = (const float*)d_in[8];
  const float* Wo = (const float*)d_in[9];
  const float* bo = (const float*)d_in[10];
  const float* W1 = (const float*)d_in[11];
  const float* b1 = (const float*)d_in[12];
  const float* W2 = (const float*)d_in[13];
  const float* b2 = (const float*)d_in[14];
  const float* ln1w = (const float*)d_in[15];
  const float* ln1b = (const float*)d_in[16];
  const float* ln2w = (const float*)d_in[17];
  const float* ln2b = (const float*)d_in[18];
  const float* lnfw = (const float*)d_in[19];
  const float* lnfb = (const float*)d_in[20];
  const float* lmh = (const float*)d_in[21];
  float* out = (float*)d_out;

  char* wsb = (char*)d_ws;
  float* h = (float*)wsb;                           // 8 MB fp32 residual
  short* x = (short*)(wsb + 8388608);               // 4 MB bf16 LN out
  char* big = wsb + 8388608 + 4194304;
  short* qkv  = (short*)big;                        // 12 MB   [S][3072]
  short* a    = (short*)(big + 12582912);           // 4 MB    [S][1024]
  short* vt   = (short*)(big + 16777216);           // 4 MB    [1024][S]
  short* fbuf = (short*)(big + 20971520);           // 16 MB   [S][4096]
  float* pproj = (float*)fbuf;                      // proj partials: 2x8MB
  float* pffn2 = (float*)big;                       // ffn2 partials: 2x8MB (qkv+a free)
  char* wdyn = big + 37748736;
  short* wqkvT = (short*)wdyn;                      // 6 MB  [3072][1024]
  short* woT   = (short*)(wdyn + 6291456);          // 2 MB  [1024][1024]
  short* w1T   = (short*)(wdyn + 8388608);          // 8 MB  [4096][1024]
  short* w2T   = (short*)(wdyn + 16777216);         // 8 MB  [1024][4096]
  float* bias3 = (float*)(wdyn + 25165824);         // 12 KB
  short* lmhB = (short*)big;                        // 103 MB, reused after layers

  embed_kernel<<<(SEQ * DIM + 255) / 256, 256, 0, stream>>>(ids, tok, pos, h);
  ln_kernel<<<SEQ, 256, 0, stream>>>(h, ln1w, ln1b, x);  // layer 0 ln1

  dim3 gQKV(SEQ / 64, QKVD / 128);                  // 32 x 24 = 768
  dim3 gPROJ(SEQ / 64, DIM / 128, 2);               // 32 x 8 x 2 = 512
  dim3 gFFN1(SEQ / 128, FFN / 128);                 // 16 x 32 = 512
  dim3 gFFN2(SEQ / 64, DIM / 128, 2);               // 32 x 8 x 2 = 512
  dim3 gV(SEQ / 256, (VOCAB + 127) / 128);          // 8 x 393 = 3144 (%8==0)

  for (int l = 0; l < NLAYER; l++) {
    Prep p;
    p.wq = Wq + (long)l * DIM * DIM; p.wk = Wk + (long)l * DIM * DIM;
    p.wv = Wv + (long)l * DIM * DIM; p.wo = Wo + (long)l * DIM * DIM;
    p.w1 = W1 + (long)l * DIM * FFN; p.w2 = W2 + (long)l * FFN * DIM;
    p.bq = bq + (long)l * DIM; p.bk = bk + (long)l * DIM; p.bv = bv + (long)l * DIM;
    p.qkvT = wqkvT; p.woT = woT; p.w1T = w1T; p.w2T = w2T; p.bias3 = bias3;
    prep_kernel<<<3073, 256, 0, stream>>>(p);

    gemm_small<false, true, true, 1, true><<<gQKV, 256, 0, stream>>>(x, wqkvT, bias3, qkv, QKVD, DIM);
    transpose_v<<<dim3(SEQ / 64, DIM / 64), 256, 0, stream>>>(qkv, vt);
    attn_mfma<<<dim3(NHEAD, SEQ / 64), 256, 0, stream>>>(qkv, vt, a);
    gemm_small<false, false, false, 2, true><<<gPROJ, 256, 0, stream>>>(a, woT, nullptr, pproj, DIM, DIM);
    reduce_ln<<<SEQ, 256, 0, stream>>>(pproj, bo + (long)l * DIM,
                                       ln2w + (long)l * DIM, ln2b + (long)l * DIM, h, x);
    gemm4<true, true, true, true><<<gFFN1, 256, 0, stream>>>(x, w1T, b1 + (long)l * FFN, fbuf, FFN, DIM);
    gemm_small<false, false, false, 2, true><<<gFFN2, 256, 0, stream>>>(fbuf, w2T, nullptr, pffn2, DIM, FFN);
    const float* nw = (l < NLAYER - 1) ? ln1w + (long)(l + 1) * DIM : lnfw;
    const float* nb = (l < NLAYER - 1) ? ln1b + (long)(l + 1) * DIM : lnfb;
    reduce_ln<<<SEQ, 256, 0, stream>>>(pffn2, b2 + (long)l * DIM, nw, nb, h, x);
  }

  conv_bf16<<<2048, 256, 0, stream>>>(lmh, lmhB, (long)VOCAB * DIM / 4);
  gemm256b<<<gV, 512, 0, stream>>>(x, lmhB, out, VOCAB, DIM);
}

// Round 13
// 1087.708 us; speedup vs baseline: 1.0588x; 1.0204x over previous
//
#include <hip/hip_runtime.h>
#include <math.h>
#include <stdint.h>

// GPT fwd, L=4 D=1024 H=16 HS=64 F=4096 V=50257 S=2048.
// Round 13: conv_bf16 eliminated — gemm256b stages B directly from the
// fp32 lm_head via reg-staging (asm global_load_dwordx4, order-pinned),
// f2bf convert, ds_write into the identical swizzled LDS slot. One
// vmcnt(2)/step retires A(t+1)+Bg(t+2) together. Everything else = R12.

#define SEQ 2048
#define DIM 1024
#define NHEAD 16
#define FFN 4096
#define VOCAB 50257
#define NLAYER 4
#define LNEPS 1e-5f
#define QKVD 3072
#define KVB 128

using bf16x8 = __attribute__((ext_vector_type(8))) short;
using s16x4  = __attribute__((ext_vector_type(4))) short;
using f32x4  = __attribute__((ext_vector_type(4))) float;
using fl4    = __attribute__((ext_vector_type(4))) float;

static __device__ __forceinline__ short f2bf(float f) {
  uint32_t u = __float_as_uint(f);
  u = (u + 0x7fffu + ((u >> 16) & 1u)) >> 16;
  return (short)u;
}
static __device__ __forceinline__ float bf2f(short s) {
  return __uint_as_float(((uint32_t)(uint16_t)s) << 16);
}
static __device__ __forceinline__ void gload_lds16(const void* g, void* l) {
  __builtin_amdgcn_global_load_lds((const __attribute__((address_space(1))) void*)g,
                                   (__attribute__((address_space(3))) void*)l, 16, 0, 0);
}

// ---------------- embedding (fp32 h) ----------------
__global__ void embed_kernel(const int* __restrict__ ids,
                             const float* __restrict__ tok,
                             const float* __restrict__ pos,
                             float* __restrict__ h) {
  int i = blockIdx.x * blockDim.x + threadIdx.x;
  if (i < SEQ * DIM) {
    int s = i / DIM, d = i % DIM;
    h[i] = tok[(long)ids[s] * DIM + d] + pos[i];
  }
}

// ---------------- layernorm: fp32 in -> bf16 out (layer0 ln1 only) ----------------
__global__ void ln_kernel(const float* __restrict__ x, const float* __restrict__ w,
                          const float* __restrict__ b, short* __restrict__ y) {
  int row = blockIdx.x;
  const float* xr = x + (long)row * DIM;
  short* yr = y + (long)row * DIM;
  int tid = threadIdx.x;
  float v0 = xr[tid], v1 = xr[tid + 256], v2 = xr[tid + 512], v3 = xr[tid + 768];
  __shared__ float red[8];
  float s = v0 + v1 + v2 + v3;
#pragma unroll
  for (int o = 32; o >= 1; o >>= 1) s += __shfl_xor(s, o);
  if ((tid & 63) == 0) red[tid >> 6] = s;
  __syncthreads();
  float mean = (red[0] + red[1] + red[2] + red[3]) * (1.f / DIM);
  float d0 = v0 - mean, d1 = v1 - mean, d2 = v2 - mean, d3 = v3 - mean;
  float q = d0 * d0 + d1 * d1 + d2 * d2 + d3 * d3;
#pragma unroll
  for (int o = 32; o >= 1; o >>= 1) q += __shfl_xor(q, o);
  if ((tid & 63) == 0) red[4 + (tid >> 6)] = q;
  __syncthreads();
  float var = (red[4] + red[5] + red[6] + red[7]) * (1.f / DIM);
  float rstd = rsqrtf(var + LNEPS);
  yr[tid]       = f2bf(d0 * rstd * w[tid] + b[tid]);
  yr[tid + 256] = f2bf(d1 * rstd * w[tid + 256] + b[tid + 256]);
  yr[tid + 512] = f2bf(d2 * rstd * w[tid + 512] + b[tid + 512]);
  yr[tid + 768] = f2bf(d3 * rstd * w[tid + 768] + b[tid + 768]);
}

// ---------------- fused: h += bias + part0 + part1; x = LN(h) bf16 ----------------
__global__ void reduce_ln(const float* __restrict__ part, const float* __restrict__ bias,
                          const float* __restrict__ lnw, const float* __restrict__ lnb,
                          float* __restrict__ h, short* __restrict__ x) {
  const long MN = (long)SEQ * DIM;
  int row = blockIdx.x, tid = threadIdx.x;
  long off = (long)row * DIM + tid * 4;
  fl4 hv = *(const fl4*)(h + off);
  fl4 p0 = *(const fl4*)(part + off);
  fl4 p1 = *(const fl4*)(part + MN + off);
  fl4 bv = *(const fl4*)(bias + tid * 4);
  float v[4];
#pragma unroll
  for (int u = 0; u < 4; u++) v[u] = hv[u] + p0[u] + p1[u] + bv[u];
  __shared__ float red[8];
  float s = v[0] + v[1] + v[2] + v[3];
#pragma unroll
  for (int o = 32; o >= 1; o >>= 1) s += __shfl_xor(s, o);
  if ((tid & 63) == 0) red[tid >> 6] = s;
  __syncthreads();
  float mean = (red[0] + red[1] + red[2] + red[3]) * (1.f / DIM);
  float d[4], q = 0.f;
#pragma unroll
  for (int u = 0; u < 4; u++) { d[u] = v[u] - mean; q += d[u] * d[u]; }
#pragma unroll
  for (int o = 32; o >= 1; o >>= 1) q += __shfl_xor(q, o);
  if ((tid & 63) == 0) red[4 + (tid >> 6)] = q;
  fl4 hw; hw[0] = v[0]; hw[1] = v[1]; hw[2] = v[2]; hw[3] = v[3];
  *(fl4*)(h + off) = hw;
  __syncthreads();
  float var = (red[4] + red[5] + red[6] + red[7]) * (1.f / DIM);
  float rstd = rsqrtf(var + LNEPS);
  fl4 w = *(const fl4*)(lnw + tid * 4);
  fl4 bb = *(const fl4*)(lnb + tid * 4);
  s16x4 o;
#pragma unroll
  for (int u = 0; u < 4; u++) o[u] = f2bf(d[u] * rstd * w[u] + bb[u]);
  *(s16x4*)(x + off) = o;
}

// ---------------- merged per-layer weight prep: 6 transposes + bias concat ----------------
struct Prep {
  const float *wq, *wk, *wv, *wo, *w1, *w2, *bq, *bk, *bv;
  short *qkvT, *woT, *w1T, *w2T;
  float* bias3;
};
__global__ void prep_kernel(Prep p) {
  int t = blockIdx.x;
  if (t >= 3072) {
    for (int k = threadIdx.x; k < QKVD; k += 256)
      p.bias3[k] = k < DIM ? p.bq[k] : (k < 2 * DIM ? p.bk[k - DIM] : p.bv[k - 2 * DIM]);
    return;
  }
  const float* in; short* out; int Kd, Nd, r0, c0;
  if (t < 1024) {
    int m = t >> 8, lt = t & 255;
    const float* srcs[4] = {p.wq, p.wk, p.wv, p.wo};
    short* dsts[4] = {p.qkvT, p.qkvT + (long)DIM * DIM, p.qkvT + (long)2 * DIM * DIM, p.woT};
    in = srcs[m]; out = dsts[m]; Kd = DIM; Nd = DIM;
    c0 = (lt & 15) * 64; r0 = (lt >> 4) * 64;
  } else if (t < 2048) {
    int lt = t - 1024; in = p.w1; out = p.w1T; Kd = DIM; Nd = FFN;
    c0 = (lt & 63) * 64; r0 = (lt >> 6) * 64;
  } else {
    int lt = t - 2048; in = p.w2; out = p.w2T; Kd = FFN; Nd = DIM;
    c0 = (lt & 15) * 64; r0 = (lt >> 4) * 64;
  }
  __shared__ float ts[64][65];
  int tid = threadIdx.x;
  int lr = tid >> 4, lc4 = (tid & 15) * 4;
#pragma unroll
  for (int i = 0; i < 4; i++) {
    fl4 v = *(const fl4*)(in + (long)(r0 + lr + i * 16) * Nd + c0 + lc4);
    ts[lr + i * 16][lc4] = v[0]; ts[lr + i * 16][lc4 + 1] = v[1];
    ts[lr + i * 16][lc4 + 2] = v[2]; ts[lr + i * 16][lc4 + 3] = v[3];
  }
  __syncthreads();
#pragma unroll
  for (int i = 0; i < 2; i++) {
    int oc = (tid >> 3) + i * 32, seg = tid & 7;
    bf16x8 o;
#pragma unroll
    for (int u = 0; u < 8; u++) o[u] = f2bf(ts[seg * 8 + u][oc]);
    *(bf16x8*)(out + (long)(c0 + oc) * Kd + r0 + seg * 8) = o;
  }
}

// ---------------- V transpose: qkv[s][2D+c] -> vt[c][s] ----------------
__global__ void transpose_v(const short* __restrict__ qkv, short* __restrict__ vt) {
  __shared__ short t[64][72];
  int s0 = blockIdx.x * 64, c0 = blockIdx.y * 64;
  int tid = threadIdx.x;
#pragma unroll
  for (int i = 0; i < 2; i++) {
    int ca = i * 256 + tid;
    int row = ca >> 3, cp = ca & 7;
    bf16x8 v = *(const bf16x8*)(qkv + (long)(s0 + row) * QKVD + 2 * DIM + c0 + cp * 8);
    *(bf16x8*)&t[row][cp * 8] = v;
  }
  __syncthreads();
#pragma unroll
  for (int i = 0; i < 2; i++) {
    int ca = i * 256 + tid;
    int crow = ca >> 3, sp = ca & 7;
    bf16x8 o;
#pragma unroll
    for (int u = 0; u < 8; u++) o[u] = t[sp * 8 + u][crow];
    *(bf16x8*)(vt + (long)(c0 + crow) * SEQ + s0 + sp * 8) = o;
  }
}

// ---------------- gemm_small: 64x128 tile, BK=32, 4 waves (QKV/proj/FFN2) ----------------
template <bool GELU, bool BIAS, bool OUTBF16, int KS, bool XCDSWZ>
__global__ __launch_bounds__(256, 4) void gemm_small(
    const short* __restrict__ A, const short* __restrict__ Bt,
    const float* __restrict__ bias, void* __restrict__ Cout, int N, int Kfull) {
  __shared__ short lds[3][(64 + 128) * 32];  // 3 x 12KB
  const int tid = threadIdx.x, wid = tid >> 6, lane = tid & 63;
  const int l16 = lane & 15, lg = lane >> 4;
  int bx = blockIdx.x, by = blockIdx.y;
  if (XCDSWZ) {
    int gx = gridDim.x, nwg = gx * gridDim.y;
    int flat = by * gx + bx;
    int nf = (flat & 7) * (nwg >> 3) + (flat >> 3);
    bx = nf % gx; by = nf / gx;
  }
  const long m0 = (long)bx * 64, n0 = (long)by * 128;
  const int K = Kfull / KS;
  const int kbase = blockIdx.z * K;
  const int NT = K / 32;
  const int wm = wid >> 1, wn = wid & 1;

#define STG(t, b)                                                               \
  {                                                                             \
    short* As_ = lds[b];                                                        \
    short* Bs_ = lds[b] + 64 * 32;                                              \
    int kk_ = kbase + (t) * 32;                                                 \
    {                                                                           \
      int row_ = tid >> 2, cp_ = tid & 3, c_ = cp_ ^ ((row_ >> 1) & 3);         \
      gload_lds16(A + (m0 + row_) * (long)Kfull + kk_ + c_ * 8,                 \
                  As_ + (wid * 64) * 8);                                        \
    }                                                                           \
    _Pragma("unroll")                                                           \
    for (int i_ = 0; i_ < 2; i_++) {                                            \
      int ca_ = i_ * 256 + tid;                                                 \
      int row_ = ca_ >> 2, cp_ = ca_ & 3, c_ = cp_ ^ ((row_ >> 1) & 3);         \
      gload_lds16(Bt + (long)(n0 + row_) * Kfull + kk_ + c_ * 8,                \
                  Bs_ + (i_ * 256 + wid * 64) * 8);                             \
    }                                                                           \
  }

  f32x4 acc[2][4] = {};
  STG(0, 0);
  STG(1, 1);
  asm volatile("s_waitcnt vmcnt(3)" ::: "memory");
  __builtin_amdgcn_s_barrier();
  __builtin_amdgcn_sched_barrier(0);

  for (int t = 0; t < NT; t++) {
    const int b = t % 3;
    if (t + 2 < NT) STG(t + 2, (t + 2) % 3);
    const short* As = lds[b];
    const short* Bs = lds[b] + 64 * 32;
    bf16x8 af[2], bfr[4];
#pragma unroll
    for (int m = 0; m < 2; m++) {
      int row = wm * 32 + m * 16 + l16;
      af[m] = *(const bf16x8*)((const char*)As + row * 64 + ((lg ^ ((row >> 1) & 3)) * 16));
    }
#pragma unroll
    for (int n = 0; n < 4; n++) {
      int row = wn * 64 + n * 16 + l16;
      bfr[n] = *(const bf16x8*)((const char*)Bs + row * 64 + ((lg ^ ((row >> 1) & 3)) * 16));
    }
    __builtin_amdgcn_s_setprio(1);
#pragma unroll
    for (int m = 0; m < 2; m++)
#pragma unroll
      for (int n = 0; n < 4; n++)
        acc[m][n] = __builtin_amdgcn_mfma_f32_16x16x32_bf16(af[m], bfr[n], acc[m][n], 0, 0, 0);
    __builtin_amdgcn_s_setprio(0);
    if (t + 2 < NT) {
      asm volatile("s_waitcnt vmcnt(3)" ::: "memory");
    } else if (t + 1 < NT) {
      asm volatile("s_waitcnt vmcnt(0)" ::: "memory");
    }
    if (t + 1 < NT) {
      __builtin_amdgcn_s_barrier();
      __builtin_amdgcn_sched_barrier(0);
    }
  }
#undef STG

  const int lr4 = lg * 4;
  if (KS == 1) {
#pragma unroll
    for (int m = 0; m < 2; m++)
#pragma unroll
      for (int n = 0; n < 4; n++)
#pragma unroll
        for (int r = 0; r < 4; r++) {
          long row = m0 + wm * 32 + m * 16 + lr4 + r;
          long col = n0 + wn * 64 + n * 16 + l16;
          float v = acc[m][n][r];
          if (BIAS) v += bias[col];
          if (GELU) v = 0.5f * v * (1.f + erff(v * 0.70710678118f));
          if (OUTBF16) ((short*)Cout)[row * (long)N + col] = f2bf(v);
          else ((float*)Cout)[row * (long)N + col] = v;
        }
  } else {
    long M = (long)gridDim.x * 64;
    float* P = (float*)Cout + (long)blockIdx.z * M * N;
#pragma unroll
    for (int m = 0; m < 2; m++)
#pragma unroll
      for (int n = 0; n < 4; n++)
#pragma unroll
        for (int r = 0; r < 4; r++) {
          long row = m0 + wm * 32 + m * 16 + lr4 + r;
          long col = n0 + wn * 64 + n * 16 + l16;
          P[row * (long)N + col] = acc[m][n][r];
        }
  }
}

// ---------------- gemm4: 128x128, BK=32, 3 blocks/CU (FFN1) ----------------
template <bool GELU, bool BIAS, bool OUTBF16, bool XCDSWZ>
__global__ __launch_bounds__(256, 3) void gemm4(
    const short* __restrict__ A, const short* __restrict__ Bt,
    const float* __restrict__ bias, void* __restrict__ Cout, int N, int Kfull) {
  __shared__ short lds[3][(128 + 128) * 32];  // 3 x 16KB
  const int tid = threadIdx.x, wid = tid >> 6, lane = tid & 63;
  const int l16 = lane & 15, lg = lane >> 4;
  int bx = blockIdx.x, by = blockIdx.y;
  if (XCDSWZ) {
    int gx = gridDim.x, nwg = gx * gridDim.y;
    int flat = by * gx + bx;
    int nf = (flat & 7) * (nwg >> 3) + (flat >> 3);
    bx = nf % gx; by = nf / gx;
  }
  const long m0 = (long)bx * 128, n0 = (long)by * 128;
  const int NT = Kfull / 32;
  const int wr = (wid >> 1) * 64, wc = (wid & 1) * 64;

#define STAGE4(t, b)                                                            \
  {                                                                             \
    short* As_ = lds[b];                                                        \
    short* Bs_ = lds[b] + 128 * 32;                                             \
    int kk_ = (t) * 32;                                                         \
    _Pragma("unroll")                                                           \
    for (int i_ = 0; i_ < 2; i_++) {                                            \
      int ca_ = i_ * 256 + tid;                                                 \
      int row_ = ca_ >> 2, cp_ = ca_ & 3, c_ = cp_ ^ ((row_ >> 1) & 3);         \
      gload_lds16(A + (m0 + row_) * (long)Kfull + kk_ + c_ * 8,                 \
                  As_ + (i_ * 256 + wid * 64) * 8);                             \
    }                                                                           \
    _Pragma("unroll")                                                           \
    for (int i_ = 0; i_ < 2; i_++) {                                            \
      int ca_ = i_ * 256 + tid;                                                 \
      int row_ = ca_ >> 2, cp_ = ca_ & 3, c_ = cp_ ^ ((row_ >> 1) & 3);         \
      gload_lds16(Bt + (long)(n0 + row_) * Kfull + kk_ + c_ * 8,                \
                  Bs_ + (i_ * 256 + wid * 64) * 8);                             \
    }                                                                           \
  }

  f32x4 acc[4][4] = {};
  STAGE4(0, 0);
  STAGE4(1, 1);
  asm volatile("s_waitcnt vmcnt(4)" ::: "memory");
  __builtin_amdgcn_s_barrier();
  __builtin_amdgcn_sched_barrier(0);

  for (int t = 0; t < NT; t++) {
    const int b = t % 3;
    if (t + 2 < NT) STAGE4(t + 2, (t + 2) % 3);
    const short* As = lds[b];
    const short* Bs = lds[b] + 128 * 32;
    bf16x8 af[4], bfr[4];
#pragma unroll
    for (int m = 0; m < 4; m++) {
      int row = wr + m * 16 + l16;
      af[m] = *(const bf16x8*)((const char*)As + row * 64 + ((lg ^ ((row >> 1) & 3)) * 16));
    }
#pragma unroll
    for (int n = 0; n < 4; n++) {
      int row = wc + n * 16 + l16;
      bfr[n] = *(const bf16x8*)((const char*)Bs + row * 64 + ((lg ^ ((row >> 1) & 3)) * 16));
    }
    __builtin_amdgcn_s_setprio(1);
#pragma unroll
    for (int m = 0; m < 4; m++)
#pragma unroll
      for (int n = 0; n < 4; n++)
        acc[m][n] = __builtin_amdgcn_mfma_f32_16x16x32_bf16(af[m], bfr[n], acc[m][n], 0, 0, 0);
    __builtin_amdgcn_s_setprio(0);
    if (t + 2 < NT) {
      asm volatile("s_waitcnt vmcnt(4)" ::: "memory");
    } else if (t + 1 < NT) {
      asm volatile("s_waitcnt vmcnt(0)" ::: "memory");
    }
    if (t + 1 < NT) {
      __builtin_amdgcn_s_barrier();
      __builtin_amdgcn_sched_barrier(0);
    }
  }
#undef STAGE4

  const int lr4 = lg * 4;
#pragma unroll
  for (int m = 0; m < 4; m++)
#pragma unroll
    for (int n = 0; n < 4; n++)
#pragma unroll
      for (int r = 0; r < 4; r++) {
        long row = m0 + wr + m * 16 + lr4 + r;
        long col = n0 + wc + n * 16 + l16;
        float v = acc[m][n][r];
        if (BIAS) v += bias[col];
        if (GELU) v = 0.5f * v * (1.f + erff(v * 0.70710678118f));
        if (OUTBF16) ((short*)Cout)[row * (long)N + col] = f2bf(v);
        else ((float*)Cout)[row * (long)N + col] = v;
      }
}

// ---------------- gemm256b v2: lm_head GEMM, fused fp32->bf16 B staging ----------------
// 256x128 tile, BK=32, 8 waves (4Mx2N, per-wave 64x64), 3x24KB LDS, 2
// blocks/CU. A: gload_lds pipeline (R12-proven). B: reg-staged from fp32
// lm_head (2x asm global_load_dwordx4/thread), f2bf, ds_write_b128 into the
// IDENTICAL swizzled slot (tid*16B). One vmcnt(2)/step retires A(t+1) AND
// Bg(t+2); sched_barrier pins the cvt/write after the wait (rule #18);
// lgkmcnt(0) before each barrier flushes the ds_write.
__global__ __launch_bounds__(512, 4) void gemm256b(
    const short* __restrict__ A, const float* __restrict__ Bt,
    float* __restrict__ C, int N, int K) {
  __shared__ short lds[3][(256 + 128) * 32];  // 3 x 24KB
  const int tid = threadIdx.x, wid = tid >> 6, lane = tid & 63;
  const int l16 = lane & 15, lg = lane >> 4;
  int bx = blockIdx.x, by = blockIdx.y;
  {  // XCD bijective remap; nwg = 8*393 = 3144 (%8 == 0)
    int gx = gridDim.x, nwg = gx * gridDim.y;
    int flat = by * gx + bx;
    int nf = (flat & 7) * (nwg >> 3) + (flat >> 3);
    bx = nf % gx; by = nf / gx;
  }
  const long m0 = (long)bx * 256, n0 = (long)by * 128;
  const int NT = K / 32;
  const int wm = wid >> 1, wn = wid & 1;

  // B staging geometry: thread -> (row 0..127, physical chunk 0..3);
  // logical chunk bc = cp ^ ((row>>1)&3); LDS dest = Bregion + tid*16B
  // (identical to the old gload layout).
  const int brow = tid >> 2, bcp = tid & 3;
  const int bc = bcp ^ ((brow >> 1) & 3);
  int browg = (int)n0 + brow;
  if (browg > N - 1) browg = N - 1;
  const float* bsrc = Bt + (long)browg * K + bc * 8;

  fl4 bg0, bg1;
#define BLOAD(t)                                                                \
  {                                                                             \
    const float* p_ = bsrc + (t) * 32;                                          \
    asm volatile("global_load_dwordx4 %0, %1, off" : "=v"(bg0) : "v"(p_));      \
    asm volatile("global_load_dwordx4 %0, %1, off" : "=v"(bg1) : "v"(p_ + 4));  \
  }
#define BWRITE(b)                                                               \
  {                                                                             \
    bf16x8 o_;                                                                  \
    _Pragma("unroll")                                                           \
    for (int u_ = 0; u_ < 4; u_++) {                                            \
      o_[u_] = f2bf(bg0[u_]);                                                   \
      o_[4 + u_] = f2bf(bg1[u_]);                                               \
    }                                                                           \
    *(bf16x8*)(lds[b] + 256 * 32 + tid * 8) = o_;                               \
  }
#define SA2(t, b)                                                               \
  {                                                                             \
    _Pragma("unroll")                                                           \
    for (int i_ = 0; i_ < 2; i_++) {                                            \
      int ca_ = i_ * 512 + tid;                                                 \
      int row_ = ca_ >> 2, cp_ = ca_ & 3, c_ = cp_ ^ ((row_ >> 1) & 3);         \
      gload_lds16(A + (m0 + row_) * (long)K + (t) * 32 + c_ * 8,                \
                  lds[b] + (i_ * 512 + wid * 64) * 8);                          \
    }                                                                           \
  }

  f32x4 acc[4][4] = {};
  // prologue: B(0),B(1) serial reg->LDS; A(0),A(1) gload; Bg(2) in flight.
  BLOAD(0);
  asm volatile("s_waitcnt vmcnt(0)" ::: "memory");
  __builtin_amdgcn_sched_barrier(0);
  BWRITE(0);
  BLOAD(1);
  asm volatile("s_waitcnt vmcnt(0)" ::: "memory");
  __builtin_amdgcn_sched_barrier(0);
  BWRITE(1);
  SA2(0, 0);
  SA2(1, 1);
  BLOAD(2);
  asm volatile("s_waitcnt vmcnt(4)" ::: "memory");  // retire A(0); keep A(1),Bg(2)
  asm volatile("s_waitcnt lgkmcnt(0)" ::: "memory");
  __builtin_amdgcn_s_barrier();
  __builtin_amdgcn_sched_barrier(0);

  for (int t = 0; t < NT; t++) {
    const int b = t % 3;
    if (t + 2 < NT) SA2(t + 2, (t + 2) % 3);
    const short* As = lds[b];
    const short* Bs = lds[b] + 256 * 32;
    bf16x8 bfr[4];
#pragma unroll
    for (int n = 0; n < 4; n++) {
      int row = wn * 64 + n * 16 + l16;
      bfr[n] = *(const bf16x8*)((const char*)Bs + row * 64 + ((lg ^ ((row >> 1) & 3)) * 16));
    }
    __builtin_amdgcn_s_setprio(1);
#pragma unroll
    for (int m = 0; m < 4; m++) {
      int row = wm * 64 + m * 16 + l16;
      bf16x8 af = *(const bf16x8*)((const char*)As + row * 64 + ((lg ^ ((row >> 1) & 3)) * 16));
#pragma unroll
      for (int n = 0; n < 4; n++)
        acc[m][n] = __builtin_amdgcn_mfma_f32_16x16x32_bf16(af, bfr[n], acc[m][n], 0, 0, 0);
    }
    __builtin_amdgcn_s_setprio(0);
    if (t + 2 < NT) {
      // retire A(t+1) [2] + Bg(t+2) [2]; leave A(t+2) [2] in flight
      asm volatile("s_waitcnt vmcnt(2)" ::: "memory");
      __builtin_amdgcn_sched_barrier(0);
      BWRITE((t + 2) % 3);
      if (t + 3 < NT) BLOAD(t + 3);
    } else {
      asm volatile("s_waitcnt vmcnt(0)" ::: "memory");
    }
    if (t + 1 < NT) {
      asm volatile("s_waitcnt lgkmcnt(0)" ::: "memory");
      __builtin_amdgcn_s_barrier();
      __builtin_amdgcn_sched_barrier(0);
    }
  }
#undef SA2
#undef BWRITE
#undef BLOAD

  const int lr4 = lg * 4;
#pragma unroll
  for (int m = 0; m < 4; m++)
#pragma unroll
    for (int n = 0; n < 4; n++)
#pragma unroll
      for (int r = 0; r < 4; r++) {
        long row = m0 + wm * 64 + m * 16 + lr4 + r;
        long col = n0 + wn * 64 + n * 16 + l16;
        if (col < N) C[row * (long)N + col] = acc[m][n][r];
      }
}

// ---------------- MFMA flash attention, KVBLK=128, dbuf staging + setprio ----------------
__global__ __launch_bounds__(256) void attn_mfma(const short* __restrict__ qkv,
                                                 const short* __restrict__ vtg,
                                                 short* __restrict__ Oa) {
  int hh = blockIdx.x, qb = blockIdx.y;
  int q0 = qb * 64;
  int tid = threadIdx.x, wv = tid >> 6, lane = tid & 63;
  int l16 = lane & 15, lg = lane >> 4;
  int hcol = hh * 64;
  __shared__ short Ks[2][KVB * 64];
  __shared__ short Vt[2][64 * KVB];
  __shared__ short Pl[4][16 * KVB];

  bf16x8 qf[2];
  {
    const short* qrow = qkv + (long)(q0 + wv * 16 + l16) * QKVD + hcol;
#pragma unroll
    for (int dc = 0; dc < 2; dc++) {
      bf16x8 t = *(const bf16x8*)(qrow + dc * 32 + lg * 8);
#pragma unroll
      for (int j = 0; j < 8; j++) t[j] = f2bf(bf2f(t[j]) * 0.125f);
      qf[dc] = t;
    }
  }
  f32x4 of[4] = {};
  float mrun[4], lrun[4];
#pragma unroll
  for (int r = 0; r < 4; r++) { mrun[r] = -3e38f; lrun[r] = 0.f; }

#define STAGEKV(kt_, b_)                                                        \
  {                                                                             \
    int k0_ = (kt_) * KVB;                                                      \
    _Pragma("unroll")                                                           \
    for (int i = 0; i < 4; i++) {                                               \
      int ca = i * 256 + tid;                                                   \
      int row = ca >> 3, cp = ca & 7, c = cp ^ (row & 7);                       \
      gload_lds16(qkv + (long)(k0_ + row) * QKVD + DIM + hcol + c * 8,          \
                  (short*)Ks[b_] + (i * 256 + wv * 64) * 8);                    \
    }                                                                           \
    _Pragma("unroll")                                                           \
    for (int i = 0; i < 4; i++) {                                               \
      int ca = i * 256 + tid;                                                   \
      int row = ca >> 4, cp = ca & 15, c = cp ^ (row & 7);                      \
      gload_lds16(vtg + (long)(hcol + row) * SEQ + k0_ + c * 8,                 \
                  (short*)Vt[b_] + (i * 256 + wv * 64) * 8);                    \
    }                                                                           \
  }

  int nt = qb / 2 + 1;
  STAGEKV(0, 0);
  asm volatile("s_waitcnt vmcnt(0)" ::: "memory");
  __builtin_amdgcn_s_barrier();

  for (int kt = 0; kt < nt; kt++) {
    const int cur = kt & 1;
    if (kt + 1 < nt) STAGEKV(kt + 1, cur ^ 1);
    int k0 = kt * KVB;

    f32x4 sacc[8] = {};
    __builtin_amdgcn_s_setprio(1);
#pragma unroll
    for (int kc = 0; kc < 8; kc++) {
      int row = kc * 16 + l16;
#pragma unroll
      for (int dc = 0; dc < 2; dc++) {
        bf16x8 kf = *(const bf16x8*)((const char*)Ks[cur] + row * 128 + (((dc * 4 + lg) ^ (row & 7)) * 16));
        sacc[kc] = __builtin_amdgcn_mfma_f32_16x16x32_bf16(qf[dc], kf, sacc[kc], 0, 0, 0);
      }
    }
    __builtin_amdgcn_s_setprio(0);

    float sv[8][4], pf[8][4];
#pragma unroll
    for (int kc = 0; kc < 8; kc++)
#pragma unroll
      for (int r = 0; r < 4; r++) sv[kc][r] = sacc[kc][r];
    if (kt == nt - 1) {
#pragma unroll
      for (int kc = 0; kc < 8; kc++)
#pragma unroll
        for (int r = 0; r < 4; r++) {
          int kg = k0 + kc * 16 + l16;
          int rg = q0 + wv * 16 + lg * 4 + r;
          if (kg > rg) sv[kc][r] = -3e38f;
        }
    }
    float corr[4];
#pragma unroll
    for (int r = 0; r < 4; r++) {
      float m01 = fmaxf(sv[0][r], sv[1][r]), m23 = fmaxf(sv[2][r], sv[3][r]);
      float m45 = fmaxf(sv[4][r], sv[5][r]), m67 = fmaxf(sv[6][r], sv[7][r]);
      float mt = fmaxf(fmaxf(m01, m23), fmaxf(m45, m67));
#pragma unroll
      for (int o = 8; o >= 1; o >>= 1) mt = fmaxf(mt, __shfl_xor(mt, o));
      float mn = fmaxf(mrun[r], mt);
      corr[r] = __expf(mrun[r] - mn);
      mrun[r] = mn;
      float ps = 0.f;
#pragma unroll
      for (int kc = 0; kc < 8; kc++) {
        float p = __expf(sv[kc][r] - mn);
        pf[kc][r] = p;
        ps += p;
      }
#pragma unroll
      for (int o = 8; o >= 1; o >>= 1) ps += __shfl_xor(ps, o);
      lrun[r] = lrun[r] * corr[r] + ps;
    }
#pragma unroll
    for (int c = 0; c < 4; c++)
#pragma unroll
      for (int r = 0; r < 4; r++) of[c][r] *= corr[r];
#pragma unroll
    for (int kc = 0; kc < 8; kc++)
#pragma unroll
      for (int r = 0; r < 4; r++) {
        int row = lg * 4 + r, col = kc * 16 + l16;
        int chunk = col >> 3;
        *(short*)((char*)Pl[wv] + row * 256 + ((chunk ^ (row & 7)) * 16) + (col & 7) * 2) = f2bf(pf[kc][r]);
      }
    bf16x8 pfr[4];
#pragma unroll
    for (int kc2 = 0; kc2 < 4; kc2++) {
      int cl = kc2 * 4 + lg;
      pfr[kc2] = *(const bf16x8*)((const char*)Pl[wv] + l16 * 256 + ((cl ^ (l16 & 7)) * 16));
    }
    __builtin_amdgcn_s_setprio(1);
#pragma unroll
    for (int c = 0; c < 4; c++)
#pragma unroll
      for (int kc2 = 0; kc2 < 4; kc2++) {
        int vrow = c * 16 + l16;
        int cl = kc2 * 4 + lg;
        bf16x8 vf = *(const bf16x8*)((const char*)Vt[cur] + vrow * 256 + ((cl ^ (vrow & 7)) * 16));
        of[c] = __builtin_amdgcn_mfma_f32_16x16x32_bf16(pfr[kc2], vf, of[c], 0, 0, 0);
      }
    __builtin_amdgcn_s_setprio(0);
    if (kt + 1 < nt) {
      asm volatile("s_waitcnt vmcnt(0)" ::: "memory");
      __builtin_amdgcn_s_barrier();
      __builtin_amdgcn_sched_barrier(0);
    }
  }
#undef STAGEKV
#pragma unroll
  for (int c = 0; c < 4; c++)
#pragma unroll
    for (int r = 0; r < 4; r++) {
      int rowg = q0 + wv * 16 + lg * 4 + r;
      int colg = hcol + c * 16 + l16;
      Oa[(long)rowg * DIM + colg] = f2bf(of[c][r] / lrun[r]);
    }
}

// ---------------- orchestration ----------------
extern "C" void kernel_launch(void* const* d_in, const int* in_sizes, int n_in,
                              void* d_out, int out_size, void* d_ws, size_t ws_size,
                              hipStream_t stream) {
  const int* ids = (const int*)d_in[0];
  const float* tok = (const float*)d_in[1];
  const float* pos = (const float*)d_in[2];
  const float* Wq = (const float*)d_in[3];
  const float* bq = (const float*)d_in[4];
  const float* Wk = (const float*)d_in[5];
  const float* bk = (const float*)d_in[6];
  const float* Wv = (const float*)d_in[7];
  const float* bv = (const float*)d_in[8];
  const float* Wo = (const float*)d_in[9];
  const float* bo = (const float*)d_in[10];
  const float* W1 = (const float*)d_in[11];
  const float* b1 = (const float*)d_in[12];
  const float* W2 = (const float*)d_in[13];
  const float* b2 = (const float*)d_in[14];
  const float* ln1w = (const float*)d_in[15];
  const float* ln1b = (const float*)d_in[16];
  const float* ln2w = (const float*)d_in[17];
  const float* ln2b = (const float*)d_in[18];
  const float* lnfw = (const float*)d_in[19];
  const float* lnfb = (const float*)d_in[20];
  const float* lmh = (const float*)d_in[21];
  float* out = (float*)d_out;

  char* wsb = (char*)d_ws;
  float* h = (float*)wsb;                           // 8 MB fp32 residual
  short* x = (short*)(wsb + 8388608);               // 4 MB bf16 LN out
  char* big = wsb + 8388608 + 4194304;
  short* qkv  = (short*)big;                        // 12 MB   [S][3072]
  short* a    = (short*)(big + 12582912);           // 4 MB    [S][1024]
  short* vt   = (short*)(big + 16777216);           // 4 MB    [1024][S]
  short* fbuf = (short*)(big + 20971520);           // 16 MB   [S][4096]
  float* pproj = (float*)fbuf;                      // proj partials: 2x8MB
  float* pffn2 = (float*)big;                       // ffn2 partials: 2x8MB (qkv+a free)
  char* wdyn = big + 37748736;
  short* wqkvT = (short*)wdyn;                      // 6 MB  [3072][1024]
  short* woT   = (short*)(wdyn + 6291456);          // 2 MB  [1024][1024]
  short* w1T   = (short*)(wdyn + 8388608);          // 8 MB  [4096][1024]
  short* w2T   = (short*)(wdyn + 16777216);         // 8 MB  [1024][4096]
  float* bias3 = (float*)(wdyn + 25165824);         // 12 KB

  embed_kernel<<<(SEQ * DIM + 255) / 256, 256, 0, stream>>>(ids, tok, pos, h);
  ln_kernel<<<SEQ, 256, 0, stream>>>(h, ln1w, ln1b, x);  // layer 0 ln1

  dim3 gQKV(SEQ / 64, QKVD / 128);                  // 32 x 24 = 768
  dim3 gPROJ(SEQ / 64, DIM / 128, 2);               // 32 x 8 x 2 = 512
  dim3 gFFN1(SEQ / 128, FFN / 128);                 // 16 x 32 = 512
  dim3 gFFN2(SEQ / 64, DIM / 128, 2);               // 32 x 8 x 2 = 512
  dim3 gV(SEQ / 256, (VOCAB + 127) / 128);          // 8 x 393 = 3144 (%8==0)

  for (int l = 0; l < NLAYER; l++) {
    Prep p;
    p.wq = Wq + (long)l * DIM * DIM; p.wk = Wk + (long)l * DIM * DIM;
    p.wv = Wv + (long)l * DIM * DIM; p.wo = Wo + (long)l * DIM * DIM;
    p.w1 = W1 + (long)l * DIM * FFN; p.w2 = W2 + (long)l * FFN * DIM;
    p.bq = bq + (long)l * DIM; p.bk = bk + (long)l * DIM; p.bv = bv + (long)l * DIM;
    p.qkvT = wqkvT; p.woT = woT; p.w1T = w1T; p.w2T = w2T; p.bias3 = bias3;
    prep_kernel<<<3073, 256, 0, stream>>>(p);

    gemm_small<false, true, true, 1, true><<<gQKV, 256, 0, stream>>>(x, wqkvT, bias3, qkv, QKVD, DIM);
    transpose_v<<<dim3(SEQ / 64, DIM / 64), 256, 0, stream>>>(qkv, vt);
    attn_mfma<<<dim3(NHEAD, SEQ / 64), 256, 0, stream>>>(qkv, vt, a);
    gemm_small<false, false, false, 2, true><<<gPROJ, 256, 0, stream>>>(a, woT, nullptr, pproj, DIM, DIM);
    reduce_ln<<<SEQ, 256, 0, stream>>>(pproj, bo + (long)l * DIM,
                                       ln2w + (long)l * DIM, ln2b + (long)l * DIM, h, x);
    gemm4<true, true, true, true><<<gFFN1, 256, 0, stream>>>(x, w1T, b1 + (long)l * FFN, fbuf, FFN, DIM);
    gemm_small<false, false, false, 2, true><<<gFFN2, 256, 0, stream>>>(fbuf, w2T, nullptr, pffn2, DIM, FFN);
    const float* nw = (l < NLAYER - 1) ? ln1w + (long)(l + 1) * DIM : lnfw;
    const float* nb = (l < NLAYER - 1) ? ln1b + (long)(l + 1) * DIM : lnfb;
    reduce_ln<<<SEQ, 256, 0, stream>>>(pffn2, b2 + (long)l * DIM, nw, nb, h, x);
  }

  gemm256b<<<gV, 512, 0, stream>>>(x, lmh, out, VOCAB, DIM);
}